// Round 2
// baseline (748.671 us; speedup 1.0000x reference)
//
#include <hip/hip_runtime.h>
#include <hip/hip_bf16.h>
#include <type_traits>

typedef __hip_bfloat16 bf16;
typedef __attribute__((ext_vector_type(8))) short short8;
typedef __attribute__((ext_vector_type(4))) float floatx4;

static constexpr int kB = 8;
static constexpr int kS = 1024;
static constexpr int kE = 512;
static constexpr int kH = 8;
static constexpr int kP = 32;
static constexpr int kTok = kB * kS;   // 8192
static constexpr int kHid = 2048;

// meta layout: [0]=pm int32 flag, [1..8]=valid_len, [9]=inputs-are-fp32 flag
// ---------------------------------------------------------------- helpers
__device__ __forceinline__ void load8f(const bf16* p, float* f) {
  uint4 u = *(const uint4*)p;
  const bf16* h = (const bf16*)&u;
#pragma unroll
  for (int e = 0; e < 8; e++) f[e] = __bfloat162float(h[e]);
}
__device__ __forceinline__ void store8b(bf16* p, const float* f) {
  uint4 u;
  bf16* h = (bf16*)&u;
#pragma unroll
  for (int e = 0; e < 8; e++) h[e] = __float2bfloat16(f[e]);
  *(uint4*)p = u;
}
__device__ __forceinline__ bool is_pad(const void* pm, int flag, int idx) {
  return flag ? (((const int*)pm)[idx] != 0)
              : (((const unsigned char*)pm)[idx] != 0);
}

// -------------------------------------------------------- dtype detection
// bf16 data drawn from ~N(0,sigma<=1): exponent field < 0x90 always.
// fp32 data read as uint16: low halves ~uniform -> ~44% have exp >= 0x90.
__global__ __launch_bounds__(256) void detect_kernel(const void* __restrict__ x,
                                                     int* __restrict__ meta) {
  __shared__ int cnt;
  if (threadIdx.x == 0) cnt = 0;
  __syncthreads();
  const unsigned short* u = (const unsigned short*)x;
  int c = 0;
  for (int i = threadIdx.x; i < 1024; i += 256) {
    int e = (u[i] >> 7) & 0xFF;
    if (e >= 0x90) c++;
  }
  if (c) atomicAdd(&cnt, c);
  __syncthreads();
  if (threadIdx.x == 0) meta[9] = (cnt > 64) ? 1 : 0;
}

// ------------------------------------------------------------- meta kernel
__global__ __launch_bounds__(256) void meta_kernel(const void* __restrict__ pm,
                                                   int* __restrict__ meta) {
  __shared__ int bigfound;
  __shared__ int cnt[kB];
  int tid = threadIdx.x;
  if (tid == 0) bigfound = 0;
  if (tid < kB) cnt[tid] = 0;
  __syncthreads();
  const unsigned int* w = (const unsigned int*)pm;
  int f = 0;
  for (int i = tid; i < 2048; i += 256)
    if (w[i] & 0xFFFFFFFEu) f = 1;
  if (f) atomicOr(&bigfound, 1);
  __syncthreads();
  int flag = bigfound ? 0 : 1;
  for (int i = tid; i < kTok; i += 256) {
    if (is_pad(pm, flag, i)) atomicAdd(&cnt[i >> 10], 1);
  }
  __syncthreads();
  if (tid == 0) meta[0] = flag;
  if (tid < kB) {
    int vl = kS - cnt[tid];
    if (vl < 1) vl = 1;
    meta[1 + tid] = vl;
  }
}

// -------------------------------------------------------- ingest kernels
// src is fp32 or bf16 per meta[9]; hi = bf16(v); lo (optional) = bf16(v-hi).
__global__ __launch_bounds__(256) void cvt_hilo_kernel(
    const void* __restrict__ src, int n, const int* __restrict__ meta,
    bf16* __restrict__ hi, bf16* __restrict__ lo) {
  int fp = meta[9];
  int i0 = (blockIdx.x * 256 + threadIdx.x) * 4;
  for (int i = i0; i < n; i += gridDim.x * 1024) {
#pragma unroll
    for (int c = 0; c < 4; c++) {
      float v = fp ? ((const float*)src)[i + c]
                   : __bfloat162float(((const bf16*)src)[i + c]);
      bf16 h = __float2bfloat16(v);
      hi[i + c] = h;
      if (lo) lo[i + c] = __float2bfloat16(v - __bfloat162float(h));
    }
  }
}
__global__ __launch_bounds__(256) void cvt_f32_kernel(
    const void* __restrict__ src, int n, const int* __restrict__ meta,
    float* __restrict__ dst) {
  int fp = meta[9];
  int i = blockIdx.x * 256 + threadIdx.x;
  if (i < n)
    dst[i] = fp ? ((const float*)src)[i]
                : __bfloat162float(((const bf16*)src)[i]);
}

// ------------------------------------------------------------- GEMM (bt)
// C[M,N] = act(A[M,K] @ W[N,K]^T + bias). A,W bf16; bias fp32; acc fp32.
static constexpr int BM = 128, BN = 128, BK = 32, LDK = 40;

template <int ACT, bool ACC, typename OUTT>
__global__ __launch_bounds__(256) void gemm_bt(
    const bf16* __restrict__ A, const bf16* __restrict__ W,
    const float* __restrict__ bias, OUTT* __restrict__ C, int M, int N,
    int K) {
  __shared__ bf16 As[BM * LDK];
  __shared__ bf16 Bs[BN * LDK];
  const int tid = threadIdx.x;
  const int lane = tid & 63;
  const int wid = tid >> 6;
  const int wm = (wid >> 1) * 64, wn = (wid & 1) * 64;
  const int m0 = blockIdx.x * BM, n0 = blockIdx.y * BN;

  floatx4 acc[4][4];
#pragma unroll
  for (int i = 0; i < 4; i++)
#pragma unroll
    for (int j = 0; j < 4; j++) acc[i][j] = (floatx4)0.0f;

  for (int kt = 0; kt < K; kt += BK) {
#pragma unroll
    for (int c = 0; c < 2; c++) {
      int v = c * 256 + tid;
      int row = v >> 2, off = (v & 3) * 8;
      *(uint4*)(&As[row * LDK + off]) =
          *(const uint4*)(&A[(size_t)(m0 + row) * K + kt + off]);
      *(uint4*)(&Bs[row * LDK + off]) =
          *(const uint4*)(&W[(size_t)(n0 + row) * K + kt + off]);
    }
    __syncthreads();
    const int ko = (lane >> 4) * 8;
    short8 af[4], bfr[4];
#pragma unroll
    for (int i = 0; i < 4; i++)
      af[i] = *(const short8*)(&As[(wm + i * 16 + (lane & 15)) * LDK + ko]);
#pragma unroll
    for (int j = 0; j < 4; j++)
      bfr[j] = *(const short8*)(&Bs[(wn + j * 16 + (lane & 15)) * LDK + ko]);
#pragma unroll
    for (int i = 0; i < 4; i++)
#pragma unroll
      for (int j = 0; j < 4; j++)
        acc[i][j] = __builtin_amdgcn_mfma_f32_16x16x32_bf16(af[i], bfr[j],
                                                            acc[i][j], 0, 0, 0);
    __syncthreads();
  }

#pragma unroll
  for (int i = 0; i < 4; i++) {
    int row_b = m0 + wm + i * 16 + (lane >> 4) * 4;
#pragma unroll
    for (int j = 0; j < 4; j++) {
      int col = n0 + wn + j * 16 + (lane & 15);
      float bv = bias ? bias[col] : 0.0f;
#pragma unroll
      for (int r = 0; r < 4; r++) {
        float v = acc[i][j][r] + bv;
        if (ACT == 1) v = 0.5f * v * (1.0f + erff(v * 0.70710678118654752f));
        else if (ACT == 2) v = 1.0f / (1.0f + expf(-v));
        size_t idx = (size_t)(row_b + r) * N + col;
        if constexpr (ACC) {
          C[idx] = C[idx] + v;
        } else if constexpr (std::is_same<OUTT, float>::value) {
          C[idx] = v;
        } else {
          C[idx] = __float2bfloat16(v);
        }
      }
    }
  }
}

// ------------------------------------------------------- local attention
__global__ __launch_bounds__(256) void local_attn_kernel(
    const bf16* __restrict__ qkv, const void* __restrict__ pm,
    const int* __restrict__ meta, bf16* __restrict__ lo) {
  int lane = threadIdx.x & 63;
  int t = blockIdx.x * 4 + (threadIdx.x >> 6);
  int b = t >> 10, s = t & 1023;
  int h = lane >> 3, sub = lane & 7;
  int flag = meta[0];
  float q[8];
  load8f(qkv + (size_t)t * 1536 + h * 64 + sub * 8, q);
  float sc[4];
  bool val[4];
#pragma unroll
  for (int w = 0; w < 4; w++) {
    int kp = s - 3 + w;
    bool v = (kp >= 0) && !is_pad(pm, flag, b * kS + kp);
    float d = 0.0f;
    if (v) {
      float kk[8];
      load8f(qkv + (size_t)(b * kS + kp) * 1536 + 512 + h * 64 + sub * 8, kk);
#pragma unroll
      for (int e = 0; e < 8; e++) d += q[e] * kk[e];
    }
    d += __shfl_xor(d, 1);
    d += __shfl_xor(d, 2);
    d += __shfl_xor(d, 4);
    sc[w] = v ? d / 8.0f : -INFINITY;
    val[w] = v;
  }
  float mx = fmaxf(fmaxf(sc[0], sc[1]), fmaxf(sc[2], sc[3]));
  float a[4] = {0.f, 0.f, 0.f, 0.f};
  if (mx != -INFINITY) {
    float ssum = 0.f;
#pragma unroll
    for (int w = 0; w < 4; w++) {
      float e = val[w] ? expf(sc[w] - mx) : 0.0f;
      a[w] = e;
      ssum += e;
    }
#pragma unroll
    for (int w = 0; w < 4; w++) a[w] /= ssum;
  }
  float o[8] = {0.f, 0.f, 0.f, 0.f, 0.f, 0.f, 0.f, 0.f};
#pragma unroll
  for (int w = 0; w < 4; w++) {
    if (val[w] && a[w] > 0.0f) {
      int kp = s - 3 + w;
      float vv[8];
      load8f(qkv + (size_t)(b * kS + kp) * 1536 + 1024 + h * 64 + sub * 8, vv);
#pragma unroll
      for (int e = 0; e < 8; e++) o[e] += a[w] * vv[e];
    }
  }
  store8b(lo + (size_t)t * kE + lane * 8, o);
}

// ------------------------------------------- fp32 -> gelu -> bf16 hi/lo
__global__ __launch_bounds__(256) void gelu_split_kernel(
    const float* __restrict__ S, bf16* __restrict__ hi, bf16* __restrict__ lo) {
  int i = (blockIdx.x * 256 + threadIdx.x) * 4;
#pragma unroll
  for (int c = 0; c < 4; c++) {
    float v = S[i + c];
    float g = 0.5f * v * (1.0f + erff(v * 0.70710678118654752f));
    bf16 a = __float2bfloat16(g);
    hi[i + c] = a;
    lo[i + c] = __float2bfloat16(g - __bfloat162float(a));
  }
}

// ----------------------------------------------------------- sampler
__global__ __launch_bounds__(256) void sampler_kernel(
    const float* __restrict__ rawf, const void* __restrict__ pm,
    const int* __restrict__ meta, int* __restrict__ sp,
    unsigned int* __restrict__ invm) {
  int t = blockIdx.x * 8 + (threadIdx.x >> 5);
  int p = threadIdx.x & 31;
  int b = t >> 10, s = t & 1023;
  int flag = meta[0];
  float off = 0.0f;
#pragma unroll
  for (int h = 0; h < kH; h++) off += tanhf(rawf[(size_t)t * 256 + h * kP + p]);
  double anchor = 0.1 + 0.8 * (double)p / 31.0;
  double sampled = anchor * (double)s + (double)off;
  double lov = fmax(0.0, (double)s - 256.0);
  sampled = fmin(fmax(sampled, lov), (double)s);
  int vlen = meta[1 + b];
  sampled = fmin(sampled, (double)(vlen - 1));
  int spv = (int)rint(sampled);
  bool inv = is_pad(pm, flag, b * kS + spv) || (spv > s) ||
             (spv >= max(0, s - 3));
  sp[(size_t)t * kP + p] = spv;
  unsigned long long m = __ballot(inv);
  int lane = threadIdx.x & 63;
  if (lane == 0) invm[t] = (unsigned int)m;
  if (lane == 32) invm[t] = (unsigned int)(m >> 32);
}

// ------------------------------------------------------ long attention
__global__ __launch_bounds__(256) void long_attn_kernel(
    const bf16* __restrict__ qd, const bf16* __restrict__ kd,
    const bf16* __restrict__ vd, const int* __restrict__ sp,
    const unsigned int* __restrict__ invm, bf16* __restrict__ ctx) {
  int lane = threadIdx.x & 63;
  int t = blockIdx.x * 4 + (threadIdx.x >> 6);
  int b = t >> 10;
  int p = lane & 31, half = lane >> 5;
  int myrow = b * kS + sp[(size_t)t * kP + p];
  bool inv = (invm[t] >> p) & 1u;
  const bf16* qr = qd + (size_t)t * kE + half * 256;
  const bf16* kr = kd + (size_t)myrow * kE + half * 256;
  float d = 0.0f;
#pragma unroll 8
  for (int it = 0; it < 32; it++) {
    float qv[8], kv[8];
    load8f(qr + it * 8, qv);
    load8f(kr + it * 8, kv);
#pragma unroll
    for (int e = 0; e < 8; e++) d += qv[e] * kv[e];
  }
  d += __shfl_xor(d, 32);
  float sc = inv ? -INFINITY : d / 22.627416997969522f;
  float mx = sc;
#pragma unroll
  for (int m = 1; m < 32; m <<= 1) mx = fmaxf(mx, __shfl_xor(mx, m));
  float e = (inv || mx == -INFINITY) ? 0.0f : expf(sc - mx);
  float ssum = e;
#pragma unroll
  for (int m = 1; m < 32; m <<= 1) ssum += __shfl_xor(ssum, m);
  float a = (ssum > 0.0f) ? e / ssum : 0.0f;
  float o[8] = {0.f, 0.f, 0.f, 0.f, 0.f, 0.f, 0.f, 0.f};
  for (int pp = 0; pp < 32; pp++) {
    float ap = __shfl(a, pp);
    int row = __shfl(myrow, pp);
    if (ap != 0.0f) {
      float vv[8];
      load8f(vd + (size_t)row * kE + lane * 8, vv);
#pragma unroll
      for (int e2 = 0; e2 < 8; e2++) o[e2] += ap * vv[e2];
    }
  }
  store8b(ctx + (size_t)t * kE + lane * 8, o);
}

// ---------------------------------------------------------------- concat
__global__ __launch_bounds__(256) void concat_kernel(
    const bf16* __restrict__ x, const bf16* __restrict__ lo,
    const bf16* __restrict__ lg, bf16* __restrict__ cat) {
  int i = blockIdx.x * 256 + threadIdx.x;
  int t = i / 192, c = i % 192;
  const bf16* src = (c < 64) ? (x + (size_t)t * kE + c * 8)
                  : (c < 128) ? (lo + (size_t)t * kE + (c - 64) * 8)
                              : (lg + (size_t)t * kE + (c - 128) * 8);
  *(uint4*)(cat + (size_t)t * 1536 + c * 8) = *(const uint4*)src;
}

// ------------------------------------------------------------------- LN1
__global__ __launch_bounds__(256) void ln1_kernel(
    const void* __restrict__ xin, const int* __restrict__ meta,
    const bf16* __restrict__ lo, const bf16* __restrict__ lg,
    const bf16* __restrict__ g, const float* __restrict__ gamma,
    const float* __restrict__ beta, bf16* __restrict__ x1b,
    float* __restrict__ x1f) {
  int lane = threadIdx.x & 63;
  int t = blockIdx.x * 4 + (threadIdx.x >> 6);
  size_t base = (size_t)t * kE + lane * 8;
  float xv[8], lov[8], lgv[8], gv[8], h[8];
  if (meta[9]) {
    const float4* xf = (const float4*)((const float*)xin + base);
    float4 a = xf[0], b2 = xf[1];
    xv[0] = a.x; xv[1] = a.y; xv[2] = a.z; xv[3] = a.w;
    xv[4] = b2.x; xv[5] = b2.y; xv[6] = b2.z; xv[7] = b2.w;
  } else {
    load8f((const bf16*)xin + base, xv);
  }
  load8f(lo + base, lov);
  load8f(lg + base, lgv);
  load8f(g + base, gv);
  float s1 = 0.f, s2 = 0.f;
#pragma unroll
  for (int e = 0; e < 8; e++) {
    h[e] = xv[e] + gv[e] * lov[e] + (1.0f - gv[e]) * lgv[e];
    s1 += h[e];
    s2 += h[e] * h[e];
  }
#pragma unroll
  for (int m = 1; m < 64; m <<= 1) {
    s1 += __shfl_xor(s1, m);
    s2 += __shfl_xor(s2, m);
  }
  float mean = s1 * (1.0f / kE);
  float var = s2 * (1.0f / kE) - mean * mean;
  float rstd = 1.0f / sqrtf(var + 1e-5f);
  float y[8];
#pragma unroll
  for (int e = 0; e < 8; e++)
    y[e] = (h[e] - mean) * rstd * gamma[lane * 8 + e] + beta[lane * 8 + e];
  store8b(x1b + base, y);
#pragma unroll
  for (int e = 0; e < 8; e++) x1f[base + e] = y[e];
}

// ------------------------------------------------------------------- LN2
__global__ __launch_bounds__(256) void ln2_kernel(
    const float* __restrict__ x1f, const float* __restrict__ ff,
    const float* __restrict__ gamma, const float* __restrict__ beta,
    const int* __restrict__ meta, void* __restrict__ out) {
  int lane = threadIdx.x & 63;
  int t = blockIdx.x * 4 + (threadIdx.x >> 6);
  size_t base = (size_t)t * kE + lane * 8;
  float h[8];
  float s1 = 0.f, s2 = 0.f;
#pragma unroll
  for (int e = 0; e < 8; e++) {
    h[e] = x1f[base + e] + ff[base + e];
    s1 += h[e];
    s2 += h[e] * h[e];
  }
#pragma unroll
  for (int m = 1; m < 64; m <<= 1) {
    s1 += __shfl_xor(s1, m);
    s2 += __shfl_xor(s2, m);
  }
  float mean = s1 * (1.0f / kE);
  float var = s2 * (1.0f / kE) - mean * mean;
  float rstd = 1.0f / sqrtf(var + 1e-5f);
  float y[8];
#pragma unroll
  for (int e = 0; e < 8; e++)
    y[e] = (h[e] - mean) * rstd * gamma[lane * 8 + e] + beta[lane * 8 + e];
  if (meta[9]) {
    float* of = (float*)out + base;
    ((float4*)of)[0] = make_float4(y[0], y[1], y[2], y[3]);
    ((float4*)of)[1] = make_float4(y[4], y[5], y[6], y[7]);
  } else {
    store8b((bf16*)out + base, y);
  }
}

// ------------------------------------------------------------------ launch
extern "C" void kernel_launch(void* const* d_in, const int* in_sizes, int n_in,
                              void* d_out, int out_size, void* d_ws,
                              size_t ws_size, hipStream_t stream) {
  const void* x = d_in[0];
  const void* pm = d_in[1];

  char* w = (char*)d_ws;
  auto alloc = [&](size_t bytes) {
    char* p = w;
    w += (bytes + 255) & ~(size_t)255;
    return p;
  };
  bf16* qkv = (bf16*)alloc((size_t)kTok * 1536 * 2);   // reuse: rawf, f_f32
  bf16* big = (bf16*)alloc((size_t)kTok * 2048 * 2);   // cat / ffn hidden
  bf16* lo_ctx = (bf16*)alloc((size_t)kTok * kE * 2);
  bf16* local_out = (bf16*)alloc((size_t)kTok * kE * 2);
  bf16* long_out = (bf16*)alloc((size_t)kTok * kE * 2);
  bf16* qd = (bf16*)alloc((size_t)kTok * kE * 2);
  bf16* kd = (bf16*)alloc((size_t)kTok * kE * 2);
  bf16* vd = (bf16*)alloc((size_t)kTok * kE * 2);
  bf16* hbuf = (bf16*)alloc((size_t)kTok * kE * 2);    // h_hi / gate hidden
  bf16* gbuf = (bf16*)alloc((size_t)kTok * kE * 2);    // gate out
  bf16* x1b = (bf16*)alloc((size_t)kTok * kE * 2);     // h_lo / x1 bf16
  float* x1f = (float*)alloc((size_t)kTok * kE * 4);   // S fp32 / x1 fp32
  int* sp = (int*)alloc((size_t)kTok * kP * 4);
  unsigned int* invm = (unsigned int*)alloc((size_t)kTok * 4);
  int* meta = (int*)alloc(256);
  bf16* x_hi = (bf16*)alloc((size_t)kTok * kE * 2);
  bf16* x_lo = (bf16*)alloc((size_t)kTok * kE * 2);
  // weight hi (+ lo for offset branch)
  bf16* ipw = (bf16*)alloc(1536 * 512 * 2);
  bf16* mow = (bf16*)alloc(512 * 512 * 2);
  bf16* dqw = (bf16*)alloc(512 * 512 * 2);
  bf16* dkw = (bf16*)alloc(512 * 512 * 2);
  bf16* dvw = (bf16*)alloc(512 * 512 * 2);
  bf16* dow = (bf16*)alloc(512 * 512 * 2);
  bf16* o1h = (bf16*)alloc(512 * 512 * 2);
  bf16* o1l = (bf16*)alloc(512 * 512 * 2);
  bf16* o2h = (bf16*)alloc(256 * 512 * 2);
  bf16* o2l = (bf16*)alloc(256 * 512 * 2);
  bf16* g1w = (bf16*)alloc(512 * 1536 * 2);
  bf16* g2w = (bf16*)alloc(512 * 512 * 2);
  bf16* f1w = (bf16*)alloc((size_t)2048 * 512 * 2);
  bf16* f2w = (bf16*)alloc((size_t)512 * 2048 * 2);
  // biases / LN params as fp32
  float* ipb = (float*)alloc(1536 * 4);
  float* mob = (float*)alloc(512 * 4);
  float* dqb = (float*)alloc(512 * 4);
  float* dkb = (float*)alloc(512 * 4);
  float* dvb = (float*)alloc(512 * 4);
  float* dob = (float*)alloc(512 * 4);
  float* o1b = (float*)alloc(512 * 4);
  float* o2b = (float*)alloc(256 * 4);
  float* g1b = (float*)alloc(512 * 4);
  float* g2b = (float*)alloc(512 * 4);
  float* n1g = (float*)alloc(512 * 4);
  float* n1bt = (float*)alloc(512 * 4);
  float* n2g = (float*)alloc(512 * 4);
  float* n2bt = (float*)alloc(512 * 4);
  float* f1b = (float*)alloc(2048 * 4);
  float* f2b = (float*)alloc(512 * 4);

  float* rawf = (float*)qkv;        // dead-qkv reuse (offset branch)
  float* f_f32 = (float*)qkv;       // dead-qkv reuse (ffn2 out)
  float* S32 = x1f;                 // off1 fp32 out (dead before LN1)
  bf16* h_hi = hbuf;
  bf16* h_lo = x1b;

  dim3 blk(256);
  detect_kernel<<<1, blk, 0, stream>>>(x, meta);
  meta_kernel<<<1, blk, 0, stream>>>(pm, meta);

  // ---- ingest
  auto cvt = [&](const void* src, int n, bf16* hi, bf16* lo) {
    cvt_hilo_kernel<<<(n / 4 + 255) / 256, blk, 0, stream>>>(src, n, meta, hi,
                                                             lo);
  };
  auto cvtf = [&](const void* src, int n, float* dst) {
    cvt_f32_kernel<<<(n + 255) / 256, blk, 0, stream>>>(src, n, meta, dst);
  };
  cvt(d_in[0], kTok * kE, x_hi, x_lo);
  cvt(d_in[2], 1536 * 512, ipw, nullptr);
  cvt(d_in[4], 512 * 512, mow, nullptr);
  cvt(d_in[6], 512 * 512, dqw, nullptr);
  cvt(d_in[8], 512 * 512, dkw, nullptr);
  cvt(d_in[10], 512 * 512, dvw, nullptr);
  cvt(d_in[12], 512 * 512, dow, nullptr);
  cvt(d_in[14], 512 * 512, o1h, o1l);
  cvt(d_in[16], 256 * 512, o2h, o2l);
  cvt(d_in[18], 512 * 1536, g1w, nullptr);
  cvt(d_in[20], 512 * 512, g2w, nullptr);
  cvt(d_in[26], 2048 * 512, f1w, nullptr);
  cvt(d_in[28], 512 * 2048, f2w, nullptr);
  cvtf(d_in[3], 1536, ipb);
  cvtf(d_in[5], 512, mob);
  cvtf(d_in[7], 512, dqb);
  cvtf(d_in[9], 512, dkb);
  cvtf(d_in[11], 512, dvb);
  cvtf(d_in[13], 512, dob);
  cvtf(d_in[15], 512, o1b);
  cvtf(d_in[17], 256, o2b);
  cvtf(d_in[19], 512, g1b);
  cvtf(d_in[21], 512, g2b);
  cvtf(d_in[22], 512, n1g);
  cvtf(d_in[23], 512, n1bt);
  cvtf(d_in[24], 512, n2g);
  cvtf(d_in[25], 512, n2bt);
  cvtf(d_in[27], 2048, f1b);
  cvtf(d_in[29], 512, f2b);

  // ---- qkv + local attention
  gemm_bt<0, false, bf16><<<dim3(64, 12), blk, 0, stream>>>(
      x_hi, ipw, ipb, qkv, kTok, 1536, kE);
  local_attn_kernel<<<2048, blk, 0, stream>>>(qkv, pm, meta, lo_ctx);
  gemm_bt<0, false, bf16><<<dim3(64, 4), blk, 0, stream>>>(
      lo_ctx, mow, mob, local_out, kTok, kE, kE);

  // ---- offset branch (hi/lo 3-pass for fp32-faithful sampling indices)
  gemm_bt<0, false, float><<<dim3(64, 4), blk, 0, stream>>>(
      x_hi, o1h, o1b, S32, kTok, kE, kE);
  gemm_bt<0, true, float><<<dim3(64, 4), blk, 0, stream>>>(
      x_hi, o1l, nullptr, S32, kTok, kE, kE);
  gemm_bt<0, true, float><<<dim3(64, 4), blk, 0, stream>>>(
      x_lo, o1h, nullptr, S32, kTok, kE, kE);
  gelu_split_kernel<<<4096, blk, 0, stream>>>(S32, h_hi, h_lo);
  gemm_bt<0, false, float><<<dim3(64, 2), blk, 0, stream>>>(
      h_hi, o2h, o2b, rawf, kTok, 256, kE);
  gemm_bt<0, true, float><<<dim3(64, 2), blk, 0, stream>>>(
      h_hi, o2l, nullptr, rawf, kTok, 256, kE);
  gemm_bt<0, true, float><<<dim3(64, 2), blk, 0, stream>>>(
      h_lo, o2h, nullptr, rawf, kTok, 256, kE);
  sampler_kernel<<<1024, blk, 0, stream>>>(rawf, pm, meta, sp, invm);

  // ---- deformable long attention
  gemm_bt<0, false, bf16><<<dim3(64, 4), blk, 0, stream>>>(
      x_hi, dqw, dqb, qd, kTok, kE, kE);
  gemm_bt<0, false, bf16><<<dim3(64, 4), blk, 0, stream>>>(
      x_hi, dkw, dkb, kd, kTok, kE, kE);
  gemm_bt<0, false, bf16><<<dim3(64, 4), blk, 0, stream>>>(
      x_hi, dvw, dvb, vd, kTok, kE, kE);
  long_attn_kernel<<<2048, blk, 0, stream>>>(qd, kd, vd, sp, invm, lo_ctx);
  gemm_bt<0, false, bf16><<<dim3(64, 4), blk, 0, stream>>>(
      lo_ctx, dow, dob, long_out, kTok, kE, kE);

  // ---- gate
  concat_kernel<<<6144, blk, 0, stream>>>(x_hi, local_out, long_out, big);
  gemm_bt<1, false, bf16><<<dim3(64, 4), blk, 0, stream>>>(
      big, g1w, g1b, hbuf, kTok, kE, 1536);
  gemm_bt<2, false, bf16><<<dim3(64, 4), blk, 0, stream>>>(
      hbuf, g2w, g2b, gbuf, kTok, kE, kE);

  // ---- fuse + LN1 + FFN + LN2
  ln1_kernel<<<2048, blk, 0, stream>>>(x, meta, local_out, long_out, gbuf, n1g,
                                       n1bt, x1b, x1f);
  gemm_bt<1, false, bf16><<<dim3(64, 16), blk, 0, stream>>>(
      x1b, f1w, f1b, big, kTok, kHid, kE);
  gemm_bt<0, false, float><<<dim3(64, 4), blk, 0, stream>>>(
      big, f2w, f2b, f_f32, kTok, kE, kHid);
  ln2_kernel<<<2048, blk, 0, stream>>>(x1f, f_f32, n2g, n2bt, meta, d_out);
}

// Round 3
// 514.164 us; speedup vs baseline: 1.4561x; 1.4561x over previous
//
#include <hip/hip_runtime.h>
#include <hip/hip_bf16.h>
#include <type_traits>

typedef __hip_bfloat16 bf16;
typedef __attribute__((ext_vector_type(8))) short short8;
typedef __attribute__((ext_vector_type(4))) float floatx4;

static constexpr int kB = 8;
static constexpr int kS = 1024;
static constexpr int kE = 512;
static constexpr int kH = 8;
static constexpr int kP = 32;
static constexpr int kTok = kB * kS;   // 8192
static constexpr int kHid = 2048;

// meta layout: [0]=pm int32 flag, [1..8]=valid_len, [9]=inputs-are-fp32 flag
// ---------------------------------------------------------------- helpers
__device__ __forceinline__ void load8f(const bf16* p, float* f) {
  uint4 u = *(const uint4*)p;
  const bf16* h = (const bf16*)&u;
#pragma unroll
  for (int e = 0; e < 8; e++) f[e] = __bfloat162float(h[e]);
}
__device__ __forceinline__ void store8b(bf16* p, const float* f) {
  uint4 u;
  bf16* h = (bf16*)&u;
#pragma unroll
  for (int e = 0; e < 8; e++) h[e] = __float2bfloat16(f[e]);
  *(uint4*)p = u;
}
__device__ __forceinline__ bool is_pad(const void* pm, int flag, int idx) {
  return flag ? (((const int*)pm)[idx] != 0)
              : (((const unsigned char*)pm)[idx] != 0);
}

// -------------------------------------------------------- dtype detection
__global__ __launch_bounds__(256) void detect_kernel(const void* __restrict__ x,
                                                     int* __restrict__ meta) {
  __shared__ int cnt;
  if (threadIdx.x == 0) cnt = 0;
  __syncthreads();
  const unsigned short* u = (const unsigned short*)x;
  int c = 0;
  for (int i = threadIdx.x; i < 1024; i += 256) {
    int e = (u[i] >> 7) & 0xFF;
    if (e >= 0x90) c++;
  }
  if (c) atomicAdd(&cnt, c);
  __syncthreads();
  if (threadIdx.x == 0) meta[9] = (cnt > 64) ? 1 : 0;
}

// ------------------------------------------------------------- meta kernel
__global__ __launch_bounds__(256) void meta_kernel(const void* __restrict__ pm,
                                                   int* __restrict__ meta) {
  __shared__ int bigfound;
  __shared__ int cnt[kB];
  int tid = threadIdx.x;
  if (tid == 0) bigfound = 0;
  if (tid < kB) cnt[tid] = 0;
  __syncthreads();
  const unsigned int* w = (const unsigned int*)pm;
  int f = 0;
  for (int i = tid; i < 2048; i += 256)
    if (w[i] & 0xFFFFFFFEu) f = 1;
  if (f) atomicOr(&bigfound, 1);
  __syncthreads();
  int flag = bigfound ? 0 : 1;
  for (int i = tid; i < kTok; i += 256) {
    if (is_pad(pm, flag, i)) atomicAdd(&cnt[i >> 10], 1);
  }
  __syncthreads();
  if (tid == 0) meta[0] = flag;
  if (tid < kB) {
    int vl = kS - cnt[tid];
    if (vl < 1) vl = 1;
    meta[1 + tid] = vl;
  }
}

// ------------------------------------------- batched ingest (one launch)
struct CvtJob { const void* src; bf16* hi; bf16* lo; int nblk; };
struct CvtJobs { CvtJob j[13]; };
__global__ __launch_bounds__(256) void cvt_all_kernel(CvtJobs jobs,
                                                      const int* __restrict__ meta) {
  int fp = meta[9];
  int b = blockIdx.x, ji = 0;
  while (b >= jobs.j[ji].nblk) { b -= jobs.j[ji].nblk; ji++; }
  CvtJob J = jobs.j[ji];
  int i = b * 1024 + threadIdx.x * 4;
  float v[4];
  if (fp) {
    float4 f = ((const float4*)J.src)[i >> 2];
    v[0] = f.x; v[1] = f.y; v[2] = f.z; v[3] = f.w;
  } else {
    uint2 u = *(const uint2*)((const bf16*)J.src + i);
    const bf16* h = (const bf16*)&u;
#pragma unroll
    for (int e = 0; e < 4; e++) v[e] = __bfloat162float(h[e]);
  }
  uint2 uh;
  bf16* hh = (bf16*)&uh;
#pragma unroll
  for (int e = 0; e < 4; e++) hh[e] = __float2bfloat16(v[e]);
  *(uint2*)(J.hi + i) = uh;
  if (J.lo) {
    uint2 ul;
    bf16* hl = (bf16*)&ul;
#pragma unroll
    for (int e = 0; e < 4; e++)
      hl[e] = __float2bfloat16(v[e] - __bfloat162float(hh[e]));
    *(uint2*)(J.lo + i) = ul;
  }
}

struct CvtFJob { const void* src; float* dst; int n; };
struct CvtFJobs { CvtFJob j[16]; };
__global__ __launch_bounds__(256) void cvt_small_kernel(CvtFJobs jobs,
                                                        const int* __restrict__ meta) {
  int fp = meta[9];
#pragma unroll 1
  for (int ji = 0; ji < 16; ji++) {
    CvtFJob J = jobs.j[ji];
    for (int i = threadIdx.x; i < J.n; i += 256)
      J.dst[i] = fp ? ((const float*)J.src)[i]
                    : __bfloat162float(((const bf16*)J.src)[i]);
  }
}

// ------------------------------------------------------------- GEMM (bt)
// C[M,N] = act(A[M,K] @ W[N,K]^T + bias). A,W bf16; bias fp32; acc fp32.
// Tile combos: (128,128) 2x2 waves of 64x64; (128,64) 4x1 waves of 32x64.
static constexpr int BK = 32, LDK = 40;

template <int BM, int BN, int ACT, bool ACC, typename OUTT>
__global__ __launch_bounds__(256) void gemm_bt(
    const bf16* __restrict__ A, const bf16* __restrict__ W,
    const float* __restrict__ bias, OUTT* __restrict__ C, int M, int N,
    int K) {
  constexpr int WR = (BM == 128 && BN == 128) ? 4 : 2;
  constexpr int WC = (BN == 128) ? 4 : 4;
  __shared__ bf16 As[BM * LDK];
  __shared__ bf16 Bs[BN * LDK];
  const int tid = threadIdx.x;
  const int lane = tid & 63;
  const int wid = tid >> 6;
  int wm, wn;
  if constexpr (BM == 128 && BN == 128) {
    wm = (wid >> 1) * 64; wn = (wid & 1) * 64;
  } else {  // 128x64
    wm = wid * 32; wn = 0;
  }
  const int m0 = blockIdx.x * BM, n0 = blockIdx.y * BN;

  floatx4 acc[WR][WC];
#pragma unroll
  for (int i = 0; i < WR; i++)
#pragma unroll
    for (int j = 0; j < WC; j++) acc[i][j] = (floatx4)0.0f;

  for (int kt = 0; kt < K; kt += BK) {
#pragma unroll
    for (int c = 0; c < BM / 64; c++) {
      int v = c * 256 + tid;
      int row = v >> 2, off = (v & 3) * 8;
      *(uint4*)(&As[row * LDK + off]) =
          *(const uint4*)(&A[(size_t)(m0 + row) * K + kt + off]);
    }
#pragma unroll
    for (int c = 0; c < BN / 64; c++) {
      int v = c * 256 + tid;
      int row = v >> 2, off = (v & 3) * 8;
      *(uint4*)(&Bs[row * LDK + off]) =
          *(const uint4*)(&W[(size_t)(n0 + row) * K + kt + off]);
    }
    __syncthreads();
    const int ko = (lane >> 4) * 8;
    short8 af[WR], bfr[WC];
#pragma unroll
    for (int i = 0; i < WR; i++)
      af[i] = *(const short8*)(&As[(wm + i * 16 + (lane & 15)) * LDK + ko]);
#pragma unroll
    for (int j = 0; j < WC; j++)
      bfr[j] = *(const short8*)(&Bs[(wn + j * 16 + (lane & 15)) * LDK + ko]);
#pragma unroll
    for (int i = 0; i < WR; i++)
#pragma unroll
      for (int j = 0; j < WC; j++)
        acc[i][j] = __builtin_amdgcn_mfma_f32_16x16x32_bf16(af[i], bfr[j],
                                                            acc[i][j], 0, 0, 0);
    __syncthreads();
  }

#pragma unroll
  for (int i = 0; i < WR; i++) {
    int row_b = m0 + wm + i * 16 + (lane >> 4) * 4;
#pragma unroll
    for (int j = 0; j < WC; j++) {
      int col = n0 + wn + j * 16 + (lane & 15);
      float bv = bias ? bias[col] : 0.0f;
#pragma unroll
      for (int r = 0; r < 4; r++) {
        float v = acc[i][j][r] + bv;
        if (ACT == 1) v = 0.5f * v * (1.0f + erff(v * 0.70710678118654752f));
        else if (ACT == 2) v = 1.0f / (1.0f + expf(-v));
        size_t idx = (size_t)(row_b + r) * N + col;
        if constexpr (ACC) {
          C[idx] = C[idx] + v;
        } else if constexpr (std::is_same<OUTT, float>::value) {
          C[idx] = v;
        } else {
          C[idx] = __float2bfloat16(v);
        }
      }
    }
  }
}

// ---------------------------------------------- fused hi/lo triple GEMM
// C = Ah@Wh^T + Ah@Wl^T + Al@Wh^T + bias (fp32 out). Offset branch only.
// Tile combos: (128,64) 4x1 waves of 32x64; (64,64) 2x2 waves of 32x32.
template <int BM, int BN>
__global__ __launch_bounds__(256) void gemm3_bt(
    const bf16* __restrict__ Ah, const bf16* __restrict__ Al,
    const bf16* __restrict__ Wh, const bf16* __restrict__ Wl,
    const float* __restrict__ bias, float* __restrict__ C, int M, int N,
    int K) {
  constexpr int WR = 2;
  constexpr int WC = (BM == 128) ? 4 : 2;
  __shared__ bf16 Ash[BM * LDK];
  __shared__ bf16 Asl[BM * LDK];
  __shared__ bf16 Bsh[BN * LDK];
  __shared__ bf16 Bsl[BN * LDK];
  const int tid = threadIdx.x;
  const int lane = tid & 63;
  const int wid = tid >> 6;
  int wm, wn;
  if constexpr (BM == 128) {
    wm = wid * 32; wn = 0;
  } else {
    wm = (wid >> 1) * 32; wn = (wid & 1) * 32;
  }
  const int m0 = blockIdx.x * BM, n0 = blockIdx.y * BN;

  floatx4 acc[WR][WC];
#pragma unroll
  for (int i = 0; i < WR; i++)
#pragma unroll
    for (int j = 0; j < WC; j++) acc[i][j] = (floatx4)0.0f;

  for (int kt = 0; kt < K; kt += BK) {
#pragma unroll
    for (int c = 0; c < BM / 64; c++) {
      int v = c * 256 + tid;
      int row = v >> 2, off = (v & 3) * 8;
      size_t g = (size_t)(m0 + row) * K + kt + off;
      *(uint4*)(&Ash[row * LDK + off]) = *(const uint4*)(&Ah[g]);
      *(uint4*)(&Asl[row * LDK + off]) = *(const uint4*)(&Al[g]);
    }
#pragma unroll
    for (int c = 0; c < BN / 64; c++) {
      int v = c * 256 + tid;
      int row = v >> 2, off = (v & 3) * 8;
      size_t g = (size_t)(n0 + row) * K + kt + off;
      *(uint4*)(&Bsh[row * LDK + off]) = *(const uint4*)(&Wh[g]);
      *(uint4*)(&Bsl[row * LDK + off]) = *(const uint4*)(&Wl[g]);
    }
    __syncthreads();
    const int ko = (lane >> 4) * 8;
    short8 ah[WR], al[WR], bh[WC], bl[WC];
#pragma unroll
    for (int i = 0; i < WR; i++) {
      int ro = (wm + i * 16 + (lane & 15)) * LDK + ko;
      ah[i] = *(const short8*)(&Ash[ro]);
      al[i] = *(const short8*)(&Asl[ro]);
    }
#pragma unroll
    for (int j = 0; j < WC; j++) {
      int ro = (wn + j * 16 + (lane & 15)) * LDK + ko;
      bh[j] = *(const short8*)(&Bsh[ro]);
      bl[j] = *(const short8*)(&Bsl[ro]);
    }
#pragma unroll
    for (int i = 0; i < WR; i++)
#pragma unroll
      for (int j = 0; j < WC; j++) {
        acc[i][j] = __builtin_amdgcn_mfma_f32_16x16x32_bf16(ah[i], bh[j],
                                                            acc[i][j], 0, 0, 0);
        acc[i][j] = __builtin_amdgcn_mfma_f32_16x16x32_bf16(ah[i], bl[j],
                                                            acc[i][j], 0, 0, 0);
        acc[i][j] = __builtin_amdgcn_mfma_f32_16x16x32_bf16(al[i], bh[j],
                                                            acc[i][j], 0, 0, 0);
      }
    __syncthreads();
  }

#pragma unroll
  for (int i = 0; i < WR; i++) {
    int row_b = m0 + wm + i * 16 + (lane >> 4) * 4;
#pragma unroll
    for (int j = 0; j < WC; j++) {
      int col = n0 + wn + j * 16 + (lane & 15);
      float bv = bias[col];
#pragma unroll
      for (int r = 0; r < 4; r++)
        C[(size_t)(row_b + r) * N + col] = acc[i][j][r] + bv;
    }
  }
}

// ------------------------------------------------------- local attention
__global__ __launch_bounds__(256) void local_attn_kernel(
    const bf16* __restrict__ qkv, const void* __restrict__ pm,
    const int* __restrict__ meta, bf16* __restrict__ lo) {
  int lane = threadIdx.x & 63;
  int t = blockIdx.x * 4 + (threadIdx.x >> 6);
  int b = t >> 10, s = t & 1023;
  int h = lane >> 3, sub = lane & 7;
  int flag = meta[0];
  float q[8];
  load8f(qkv + (size_t)t * 1536 + h * 64 + sub * 8, q);
  float sc[4];
  bool val[4];
#pragma unroll
  for (int w = 0; w < 4; w++) {
    int kp = s - 3 + w;
    bool v = (kp >= 0) && !is_pad(pm, flag, b * kS + kp);
    float d = 0.0f;
    if (v) {
      float kk[8];
      load8f(qkv + (size_t)(b * kS + kp) * 1536 + 512 + h * 64 + sub * 8, kk);
#pragma unroll
      for (int e = 0; e < 8; e++) d += q[e] * kk[e];
    }
    d += __shfl_xor(d, 1);
    d += __shfl_xor(d, 2);
    d += __shfl_xor(d, 4);
    sc[w] = v ? d / 8.0f : -INFINITY;
    val[w] = v;
  }
  float mx = fmaxf(fmaxf(sc[0], sc[1]), fmaxf(sc[2], sc[3]));
  float a[4] = {0.f, 0.f, 0.f, 0.f};
  if (mx != -INFINITY) {
    float ssum = 0.f;
#pragma unroll
    for (int w = 0; w < 4; w++) {
      float e = val[w] ? expf(sc[w] - mx) : 0.0f;
      a[w] = e;
      ssum += e;
    }
#pragma unroll
    for (int w = 0; w < 4; w++) a[w] /= ssum;
  }
  float o[8] = {0.f, 0.f, 0.f, 0.f, 0.f, 0.f, 0.f, 0.f};
#pragma unroll
  for (int w = 0; w < 4; w++) {
    if (val[w] && a[w] > 0.0f) {
      int kp = s - 3 + w;
      float vv[8];
      load8f(qkv + (size_t)(b * kS + kp) * 1536 + 1024 + h * 64 + sub * 8, vv);
#pragma unroll
      for (int e = 0; e < 8; e++) o[e] += a[w] * vv[e];
    }
  }
  store8b(lo + (size_t)t * kE + lane * 8, o);
}

// ------------------------------------------- fp32 -> gelu -> bf16 hi/lo
__global__ __launch_bounds__(256) void gelu_split_kernel(
    const float* __restrict__ S, bf16* __restrict__ hi, bf16* __restrict__ lo) {
  int i = (blockIdx.x * 256 + threadIdx.x) * 4;
#pragma unroll
  for (int c = 0; c < 4; c++) {
    float v = S[i + c];
    float g = 0.5f * v * (1.0f + erff(v * 0.70710678118654752f));
    bf16 a = __float2bfloat16(g);
    hi[i + c] = a;
    lo[i + c] = __float2bfloat16(g - __bfloat162float(a));
  }
}

// ----------------------------------------------------------- sampler
__global__ __launch_bounds__(256) void sampler_kernel(
    const float* __restrict__ rawf, const void* __restrict__ pm,
    const int* __restrict__ meta, int* __restrict__ sp,
    unsigned int* __restrict__ invm) {
  int t = blockIdx.x * 8 + (threadIdx.x >> 5);
  int p = threadIdx.x & 31;
  int b = t >> 10, s = t & 1023;
  int flag = meta[0];
  float off = 0.0f;
#pragma unroll
  for (int h = 0; h < kH; h++) off += tanhf(rawf[(size_t)t * 256 + h * kP + p]);
  double anchor = 0.1 + 0.8 * (double)p / 31.0;
  double sampled = anchor * (double)s + (double)off;
  double lov = fmax(0.0, (double)s - 256.0);
  sampled = fmin(fmax(sampled, lov), (double)s);
  int vlen = meta[1 + b];
  sampled = fmin(sampled, (double)(vlen - 1));
  int spv = (int)rint(sampled);
  bool inv = is_pad(pm, flag, b * kS + spv) || (spv > s) ||
             (spv >= max(0, s - 3));
  sp[(size_t)t * kP + p] = spv;
  unsigned long long m = __ballot(inv);
  int lane = threadIdx.x & 63;
  if (lane == 0) invm[t] = (unsigned int)m;
  if (lane == 32) invm[t] = (unsigned int)(m >> 32);
}

// ------------------------------------------------------ long attention
// qkvd layout per row (1536): [qd 0:512 | kd 512:1024 | vd 1024:1536].
// One wave per token. QK: per-sample fully-coalesced K-row load + butterfly
// reduce. XCD swizzle: one XCD covers one contiguous batch (K window L2-hot).
__global__ __launch_bounds__(256) void long_attn_kernel(
    const bf16* __restrict__ qkvd, const int* __restrict__ sp,
    const unsigned int* __restrict__ invm, bf16* __restrict__ ctx) {
  int lane = threadIdx.x & 63;
  int bid = blockIdx.x;
  int sbid = (bid & 7) * 256 + (bid >> 3);  // XCD-contiguous token ranges
  int t = sbid * 4 + (threadIdx.x >> 6);
  int b = t >> 10;
  int p = lane & 31;
  int row_abs = b * kS + sp[(size_t)t * kP + p];
  float q[8];
  load8f(qkvd + (size_t)t * 1536 + lane * 8, q);
  float sc_mine = 0.0f;
#pragma unroll 4
  for (int pp = 0; pp < 32; pp++) {
    int row = __shfl(row_abs, pp);
    float kk[8];
    load8f(qkvd + (size_t)row * 1536 + 512 + lane * 8, kk);
    float d = 0.0f;
#pragma unroll
    for (int e = 0; e < 8; e++) d += q[e] * kk[e];
#pragma unroll
    for (int m = 1; m < 64; m <<= 1) d += __shfl_xor(d, m);
    if (p == pp) sc_mine = d;
  }
  bool inv = (invm[t] >> p) & 1u;
  float sc = inv ? -INFINITY : sc_mine / 22.627416997969522f;  // sqrt(512)
  float mx = sc;
#pragma unroll
  for (int m = 1; m < 32; m <<= 1) mx = fmaxf(mx, __shfl_xor(mx, m));
  float e = (inv || mx == -INFINITY) ? 0.0f : expf(sc - mx);
  float ssum = e;
#pragma unroll
  for (int m = 1; m < 32; m <<= 1) ssum += __shfl_xor(ssum, m);
  float a = (ssum > 0.0f) ? e / ssum : 0.0f;
  float o[8] = {0.f, 0.f, 0.f, 0.f, 0.f, 0.f, 0.f, 0.f};
#pragma unroll 4
  for (int pp = 0; pp < 32; pp++) {
    float ap = __shfl(a, pp);
    int row = __shfl(row_abs, pp);
    if (ap != 0.0f) {
      float vv[8];
      load8f(qkvd + (size_t)row * 1536 + 1024 + lane * 8, vv);
#pragma unroll
      for (int e2 = 0; e2 < 8; e2++) o[e2] += ap * vv[e2];
    }
  }
  store8b(ctx + (size_t)t * kE + lane * 8, o);
}

// ---------------------------------------------------------------- concat
__global__ __launch_bounds__(256) void concat_kernel(
    const bf16* __restrict__ x, const bf16* __restrict__ lo,
    const bf16* __restrict__ lg, bf16* __restrict__ cat) {
  int i = blockIdx.x * 256 + threadIdx.x;
  int t = i / 192, c = i % 192;
  const bf16* src = (c < 64) ? (x + (size_t)t * kE + c * 8)
                  : (c < 128) ? (lo + (size_t)t * kE + (c - 64) * 8)
                              : (lg + (size_t)t * kE + (c - 128) * 8);
  *(uint4*)(cat + (size_t)t * 1536 + c * 8) = *(const uint4*)src;
}

// ------------------------------------------------------------------- LN1
__global__ __launch_bounds__(256) void ln1_kernel(
    const void* __restrict__ xin, const int* __restrict__ meta,
    const bf16* __restrict__ lo, const bf16* __restrict__ lg,
    const bf16* __restrict__ g, const float* __restrict__ gamma,
    const float* __restrict__ beta, bf16* __restrict__ x1b,
    float* __restrict__ x1f) {
  int lane = threadIdx.x & 63;
  int t = blockIdx.x * 4 + (threadIdx.x >> 6);
  size_t base = (size_t)t * kE + lane * 8;
  float xv[8], lov[8], lgv[8], gv[8], h[8];
  if (meta[9]) {
    const float4* xf = (const float4*)((const float*)xin + base);
    float4 a = xf[0], b2 = xf[1];
    xv[0] = a.x; xv[1] = a.y; xv[2] = a.z; xv[3] = a.w;
    xv[4] = b2.x; xv[5] = b2.y; xv[6] = b2.z; xv[7] = b2.w;
  } else {
    load8f((const bf16*)xin + base, xv);
  }
  load8f(lo + base, lov);
  load8f(lg + base, lgv);
  load8f(g + base, gv);
  float s1 = 0.f, s2 = 0.f;
#pragma unroll
  for (int e = 0; e < 8; e++) {
    h[e] = xv[e] + gv[e] * lov[e] + (1.0f - gv[e]) * lgv[e];
    s1 += h[e];
    s2 += h[e] * h[e];
  }
#pragma unroll
  for (int m = 1; m < 64; m <<= 1) {
    s1 += __shfl_xor(s1, m);
    s2 += __shfl_xor(s2, m);
  }
  float mean = s1 * (1.0f / kE);
  float var = s2 * (1.0f / kE) - mean * mean;
  float rstd = 1.0f / sqrtf(var + 1e-5f);
  float y[8];
#pragma unroll
  for (int e = 0; e < 8; e++)
    y[e] = (h[e] - mean) * rstd * gamma[lane * 8 + e] + beta[lane * 8 + e];
  store8b(x1b + base, y);
#pragma unroll
  for (int e = 0; e < 8; e++) x1f[base + e] = y[e];
}

// ------------------------------------------------------------------- LN2
__global__ __launch_bounds__(256) void ln2_kernel(
    const float* __restrict__ x1f, const float* __restrict__ ff,
    const float* __restrict__ gamma, const float* __restrict__ beta,
    const int* __restrict__ meta, void* __restrict__ out) {
  int lane = threadIdx.x & 63;
  int t = blockIdx.x * 4 + (threadIdx.x >> 6);
  size_t base = (size_t)t * kE + lane * 8;
  float h[8];
  float s1 = 0.f, s2 = 0.f;
#pragma unroll
  for (int e = 0; e < 8; e++) {
    h[e] = x1f[base + e] + ff[base + e];
    s1 += h[e];
    s2 += h[e] * h[e];
  }
#pragma unroll
  for (int m = 1; m < 64; m <<= 1) {
    s1 += __shfl_xor(s1, m);
    s2 += __shfl_xor(s2, m);
  }
  float mean = s1 * (1.0f / kE);
  float var = s2 * (1.0f / kE) - mean * mean;
  float rstd = 1.0f / sqrtf(var + 1e-5f);
  float y[8];
#pragma unroll
  for (int e = 0; e < 8; e++)
    y[e] = (h[e] - mean) * rstd * gamma[lane * 8 + e] + beta[lane * 8 + e];
  if (meta[9]) {
    float* of = (float*)out + base;
    ((float4*)of)[0] = make_float4(y[0], y[1], y[2], y[3]);
    ((float4*)of)[1] = make_float4(y[4], y[5], y[6], y[7]);
  } else {
    store8b((bf16*)out + base, y);
  }
}

// ------------------------------------------------------------------ launch
extern "C" void kernel_launch(void* const* d_in, const int* in_sizes, int n_in,
                              void* d_out, int out_size, void* d_ws,
                              size_t ws_size, hipStream_t stream) {
  const void* x = d_in[0];
  const void* pm = d_in[1];

  char* w = (char*)d_ws;
  auto alloc = [&](size_t bytes) {
    char* p = w;
    w += (bytes + 255) & ~(size_t)255;
    return p;
  };
  bf16* qkv = (bf16*)alloc((size_t)kTok * 1536 * 2);   // reuse: rawf, f_f32
  bf16* qkvd = (bf16*)alloc((size_t)kTok * 1536 * 2);  // deformable q|k|v
  bf16* big = (bf16*)alloc((size_t)kTok * 2048 * 2);   // cat / ffn hidden
  bf16* lo_ctx = (bf16*)alloc((size_t)kTok * kE * 2);
  bf16* local_out = (bf16*)alloc((size_t)kTok * kE * 2);
  bf16* long_out = (bf16*)alloc((size_t)kTok * kE * 2);
  bf16* hbuf = (bf16*)alloc((size_t)kTok * kE * 2);    // h_hi / gate hidden
  bf16* gbuf = (bf16*)alloc((size_t)kTok * kE * 2);    // gate out
  bf16* x1b = (bf16*)alloc((size_t)kTok * kE * 2);     // h_lo / x1 bf16
  float* x1f = (float*)alloc((size_t)kTok * kE * 4);   // S fp32 / x1 fp32
  int* sp = (int*)alloc((size_t)kTok * kP * 4);
  unsigned int* invm = (unsigned int*)alloc((size_t)kTok * 4);
  int* meta = (int*)alloc(256);
  bf16* x_hi = (bf16*)alloc((size_t)kTok * kE * 2);
  bf16* x_lo = (bf16*)alloc((size_t)kTok * kE * 2);
  bf16* ipw = (bf16*)alloc(1536 * 512 * 2);
  bf16* mow = (bf16*)alloc(512 * 512 * 2);
  bf16* dqkv_w = (bf16*)alloc(1536 * 512 * 2);  // dq|dk|dv concatenated
  bf16* dow = (bf16*)alloc(512 * 512 * 2);
  bf16* o1h = (bf16*)alloc(512 * 512 * 2);
  bf16* o1l = (bf16*)alloc(512 * 512 * 2);
  bf16* o2h = (bf16*)alloc(256 * 512 * 2);
  bf16* o2l = (bf16*)alloc(256 * 512 * 2);
  bf16* g1w = (bf16*)alloc(512 * 1536 * 2);
  bf16* g2w = (bf16*)alloc(512 * 512 * 2);
  bf16* f1w = (bf16*)alloc((size_t)2048 * 512 * 2);
  bf16* f2w = (bf16*)alloc((size_t)512 * 2048 * 2);
  float* ipb = (float*)alloc(1536 * 4);
  float* mob = (float*)alloc(512 * 4);
  float* dqkv_b = (float*)alloc(1536 * 4);
  float* dob = (float*)alloc(512 * 4);
  float* o1b = (float*)alloc(512 * 4);
  float* o2b = (float*)alloc(256 * 4);
  float* g1b = (float*)alloc(512 * 4);
  float* g2b = (float*)alloc(512 * 4);
  float* n1g = (float*)alloc(512 * 4);
  float* n1bt = (float*)alloc(512 * 4);
  float* n2g = (float*)alloc(512 * 4);
  float* n2bt = (float*)alloc(512 * 4);
  float* f1b = (float*)alloc(2048 * 4);
  float* f2b = (float*)alloc(512 * 4);

  float* rawf = (float*)qkv;   // dead-qkv reuse (offset branch)
  float* f_f32 = (float*)qkv;  // dead-qkv reuse (ffn2 out)
  float* S32 = x1f;            // off1 fp32 out (dead before LN1)
  bf16* h_hi = hbuf;
  bf16* h_lo = x1b;

  dim3 blk(256);
  detect_kernel<<<1, blk, 0, stream>>>(x, meta);
  meta_kernel<<<1, blk, 0, stream>>>(pm, meta);

  // ---- batched ingest (2 launches)
  CvtJobs J;
  auto job = [](const void* s, bf16* hi, bf16* lo, int n) {
    CvtJob j; j.src = s; j.hi = hi; j.lo = lo; j.nblk = n >> 10; return j;
  };
  J.j[0] = job(d_in[0], x_hi, x_lo, kTok * kE);
  J.j[1] = job(d_in[2], ipw, nullptr, 1536 * 512);
  J.j[2] = job(d_in[4], mow, nullptr, 512 * 512);
  J.j[3] = job(d_in[6], dqkv_w, nullptr, 512 * 512);
  J.j[4] = job(d_in[8], dqkv_w + 512 * 512, nullptr, 512 * 512);
  J.j[5] = job(d_in[10], dqkv_w + 1024 * 512, nullptr, 512 * 512);
  J.j[6] = job(d_in[12], dow, nullptr, 512 * 512);
  J.j[7] = job(d_in[14], o1h, o1l, 512 * 512);
  J.j[8] = job(d_in[16], o2h, o2l, 256 * 512);
  J.j[9] = job(d_in[18], g1w, nullptr, 512 * 1536);
  J.j[10] = job(d_in[20], g2w, nullptr, 512 * 512);
  J.j[11] = job(d_in[26], f1w, nullptr, 2048 * 512);
  J.j[12] = job(d_in[28], f2w, nullptr, 512 * 2048);
  int totblk = 0;
  for (int i = 0; i < 13; i++) totblk += J.j[i].nblk;
  cvt_all_kernel<<<totblk, blk, 0, stream>>>(J, meta);

  CvtFJobs JF;
  auto fjob = [](const void* s, float* d, int n) {
    CvtFJob j; j.src = s; j.dst = d; j.n = n; return j;
  };
  JF.j[0] = fjob(d_in[3], ipb, 1536);
  JF.j[1] = fjob(d_in[5], mob, 512);
  JF.j[2] = fjob(d_in[7], dqkv_b, 512);
  JF.j[3] = fjob(d_in[9], dqkv_b + 512, 512);
  JF.j[4] = fjob(d_in[11], dqkv_b + 1024, 512);
  JF.j[5] = fjob(d_in[13], dob, 512);
  JF.j[6] = fjob(d_in[15], o1b, 512);
  JF.j[7] = fjob(d_in[17], o2b, 256);
  JF.j[8] = fjob(d_in[19], g1b, 512);
  JF.j[9] = fjob(d_in[21], g2b, 512);
  JF.j[10] = fjob(d_in[22], n1g, 512);
  JF.j[11] = fjob(d_in[23], n1bt, 512);
  JF.j[12] = fjob(d_in[24], n2g, 512);
  JF.j[13] = fjob(d_in[25], n2bt, 512);
  JF.j[14] = fjob(d_in[27], f1b, 2048);
  JF.j[15] = fjob(d_in[29], f2b, 512);
  cvt_small_kernel<<<1, blk, 0, stream>>>(JF, meta);

  // ---- qkv + local attention
  gemm_bt<128, 128, 0, false, bf16><<<dim3(64, 12), blk, 0, stream>>>(
      x_hi, ipw, ipb, qkv, kTok, 1536, kE);
  local_attn_kernel<<<2048, blk, 0, stream>>>(qkv, pm, meta, lo_ctx);
  gemm_bt<128, 64, 0, false, bf16><<<dim3(64, 8), blk, 0, stream>>>(
      lo_ctx, mow, mob, local_out, kTok, kE, kE);

  // ---- offset branch (fused hi/lo triples)
  gemm3_bt<128, 64><<<dim3(64, 8), blk, 0, stream>>>(
      x_hi, x_lo, o1h, o1l, o1b, S32, kTok, kE, kE);
  gelu_split_kernel<<<4096, blk, 0, stream>>>(S32, h_hi, h_lo);
  gemm3_bt<64, 64><<<dim3(128, 4), blk, 0, stream>>>(
      h_hi, h_lo, o2h, o2l, o2b, rawf, kTok, 256, kE);
  sampler_kernel<<<1024, blk, 0, stream>>>(rawf, pm, meta, sp, invm);

  // ---- deformable long attention
  gemm_bt<128, 128, 0, false, bf16><<<dim3(64, 12), blk, 0, stream>>>(
      x_hi, dqkv_w, dqkv_b, qkvd, kTok, 1536, kE);
  long_attn_kernel<<<2048, blk, 0, stream>>>(qkvd, sp, invm, lo_ctx);
  gemm_bt<128, 64, 0, false, bf16><<<dim3(64, 8), blk, 0, stream>>>(
      lo_ctx, dow, dob, long_out, kTok, kE, kE);

  // ---- gate
  concat_kernel<<<6144, blk, 0, stream>>>(x_hi, local_out, long_out, big);
  gemm_bt<128, 64, 1, false, bf16><<<dim3(64, 8), blk, 0, stream>>>(
      big, g1w, g1b, hbuf, kTok, kE, 1536);
  gemm_bt<128, 64, 2, false, bf16><<<dim3(64, 8), blk, 0, stream>>>(
      hbuf, g2w, g2b, gbuf, kTok, kE, kE);

  // ---- fuse + LN1 + FFN + LN2
  ln1_kernel<<<2048, blk, 0, stream>>>(x, meta, local_out, long_out, gbuf, n1g,
                                       n1bt, x1b, x1f);
  gemm_bt<128, 128, 1, false, bf16><<<dim3(64, 16), blk, 0, stream>>>(
      x1b, f1w, f1b, big, kTok, kHid, kE);
  gemm_bt<128, 64, 0, false, float><<<dim3(64, 8), blk, 0, stream>>>(
      big, f2w, f2b, f_f32, kTok, kE, kHid);
  ln2_kernel<<<2048, blk, 0, stream>>>(x1f, f_f32, n2g, n2bt, meta, d_out);
}

// Round 4
// 489.787 us; speedup vs baseline: 1.5286x; 1.0498x over previous
//
#include <hip/hip_runtime.h>
#include <hip/hip_bf16.h>
#include <type_traits>

typedef __hip_bfloat16 bf16;
typedef __attribute__((ext_vector_type(8))) short short8;
typedef __attribute__((ext_vector_type(4))) float floatx4;

static constexpr int kB = 8;
static constexpr int kS = 1024;
static constexpr int kE = 512;
static constexpr int kH = 8;
static constexpr int kP = 32;
static constexpr int kTok = kB * kS;   // 8192
static constexpr int kHid = 2048;

// meta layout: [0]=pm int32 flag, [1..8]=valid_len, [9]=inputs-are-fp32 flag
// ---------------------------------------------------------------- helpers
__device__ __forceinline__ void load8f(const bf16* p, float* f) {
  uint4 u = *(const uint4*)p;
  const bf16* h = (const bf16*)&u;
#pragma unroll
  for (int e = 0; e < 8; e++) f[e] = __bfloat162float(h[e]);
}
__device__ __forceinline__ void store8b(bf16* p, const float* f) {
  uint4 u;
  bf16* h = (bf16*)&u;
#pragma unroll
  for (int e = 0; e < 8; e++) h[e] = __float2bfloat16(f[e]);
  *(uint4*)p = u;
}
__device__ __forceinline__ bool is_pad(const void* pm, int flag, int idx) {
  return flag ? (((const int*)pm)[idx] != 0)
              : (((const unsigned char*)pm)[idx] != 0);
}
// fast gelu (tanh form, hw exp). max |err| vs exact ~3e-4 — used only where
// downstream is smooth (ffn1, gate1). Offset branch keeps exact erff.
__device__ __forceinline__ float fast_gelu(float x) {
  float u = x * (0.7978845608f + 0.044714998f * x * x);
  float e = __expf(2.0f * u);
  float t = 1.0f - 2.0f / (e + 1.0f);
  return 0.5f * x * (1.0f + t);
}

// -------------------------------------------------------- dtype detection
__global__ __launch_bounds__(256) void detect_kernel(const void* __restrict__ x,
                                                     int* __restrict__ meta) {
  __shared__ int cnt;
  if (threadIdx.x == 0) cnt = 0;
  __syncthreads();
  const unsigned short* u = (const unsigned short*)x;
  int c = 0;
  for (int i = threadIdx.x; i < 1024; i += 256) {
    int e = (u[i] >> 7) & 0xFF;
    if (e >= 0x90) c++;
  }
  if (c) atomicAdd(&cnt, c);
  __syncthreads();
  if (threadIdx.x == 0) meta[9] = (cnt > 64) ? 1 : 0;
}

// ------------------------------------------------------------- meta kernel
__global__ __launch_bounds__(256) void meta_kernel(const void* __restrict__ pm,
                                                   int* __restrict__ meta) {
  __shared__ int bigfound;
  __shared__ int cnt[kB];
  int tid = threadIdx.x;
  if (tid == 0) bigfound = 0;
  if (tid < kB) cnt[tid] = 0;
  __syncthreads();
  const unsigned int* w = (const unsigned int*)pm;
  int f = 0;
  for (int i = tid; i < 2048; i += 256)
    if (w[i] & 0xFFFFFFFEu) f = 1;
  if (f) atomicOr(&bigfound, 1);
  __syncthreads();
  int flag = bigfound ? 0 : 1;
  for (int i = tid; i < kTok; i += 256) {
    if (is_pad(pm, flag, i)) atomicAdd(&cnt[i >> 10], 1);
  }
  __syncthreads();
  if (tid == 0) meta[0] = flag;
  if (tid < kB) {
    int vl = kS - cnt[tid];
    if (vl < 1) vl = 1;
    meta[1 + tid] = vl;
  }
}

// ------------------------------------------- batched ingest (one launch)
struct CvtJob { const void* src; bf16* hi; bf16* lo; int nblk; };
struct CvtJobs { CvtJob j[13]; };
__global__ __launch_bounds__(256) void cvt_all_kernel(CvtJobs jobs,
                                                      const int* __restrict__ meta) {
  int fp = meta[9];
  int b = blockIdx.x, ji = 0;
  while (b >= jobs.j[ji].nblk) { b -= jobs.j[ji].nblk; ji++; }
  CvtJob J = jobs.j[ji];
  int i = b * 1024 + threadIdx.x * 4;
  float v[4];
  if (fp) {
    float4 f = ((const float4*)J.src)[i >> 2];
    v[0] = f.x; v[1] = f.y; v[2] = f.z; v[3] = f.w;
  } else {
    uint2 u = *(const uint2*)((const bf16*)J.src + i);
    const bf16* h = (const bf16*)&u;
#pragma unroll
    for (int e = 0; e < 4; e++) v[e] = __bfloat162float(h[e]);
  }
  uint2 uh;
  bf16* hh = (bf16*)&uh;
#pragma unroll
  for (int e = 0; e < 4; e++) hh[e] = __float2bfloat16(v[e]);
  *(uint2*)(J.hi + i) = uh;
  if (J.lo) {
    uint2 ul;
    bf16* hl = (bf16*)&ul;
#pragma unroll
    for (int e = 0; e < 4; e++)
      hl[e] = __float2bfloat16(v[e] - __bfloat162float(hh[e]));
    *(uint2*)(J.lo + i) = ul;
  }
}

struct CvtFJob { const void* src; float* dst; int n; };
struct CvtFJobs { CvtFJob j[16]; };
__global__ __launch_bounds__(256) void cvt_small_kernel(CvtFJobs jobs,
                                                        const int* __restrict__ meta) {
  int fp = meta[9];
#pragma unroll 1
  for (int ji = 0; ji < 16; ji++) {
    CvtFJob J = jobs.j[ji];
    for (int i = threadIdx.x; i < J.n; i += 256)
      J.dst[i] = fp ? ((const float*)J.src)[i]
                    : __bfloat162float(((const bf16*)J.src)[i]);
  }
}

// ------------------------------------------------------------- GEMM core
// C[M,N] = act(A[M,K] @ W[N,K]^T + bias). Operand-SWAPPED mfma: lane's 4
// acc regs = 4 consecutive N-columns -> packed 8B/16B stores.
// elem (i,j,r): row = m0+wm+i*16+(lane&15), col = n0+wn+j*16+(lane>>4)*4+r
static constexpr int BK = 32, LDK = 40;

template <int BM, int BN, int ACT, typename OUTT>
__device__ __forceinline__ void gemm_core(const bf16* __restrict__ A,
                                          const bf16* __restrict__ W,
                                          const float* __restrict__ bias,
                                          OUTT* __restrict__ C, int N, int K,
                                          int m0, int n0) {
  constexpr int WR = (BM == 128 && BN == 128) ? 4 : 2;
  constexpr int WC = 4;
  __shared__ bf16 As[BM * LDK];
  __shared__ bf16 Bs[BN * LDK];
  const int tid = threadIdx.x;
  const int lane = tid & 63;
  const int wid = tid >> 6;
  int wm, wn;
  if constexpr (BM == 128 && BN == 128) {
    wm = (wid >> 1) * 64; wn = (wid & 1) * 64;
  } else {  // 128x64
    wm = wid * 32; wn = 0;
  }

  floatx4 acc[WR][WC];
#pragma unroll
  for (int i = 0; i < WR; i++)
#pragma unroll
    for (int j = 0; j < WC; j++) acc[i][j] = (floatx4)0.0f;

  for (int kt = 0; kt < K; kt += BK) {
#pragma unroll
    for (int c = 0; c < BM / 64; c++) {
      int v = c * 256 + tid;
      int row = v >> 2, off = (v & 3) * 8;
      *(uint4*)(&As[row * LDK + off]) =
          *(const uint4*)(&A[(size_t)(m0 + row) * K + kt + off]);
    }
#pragma unroll
    for (int c = 0; c < BN / 64; c++) {
      int v = c * 256 + tid;
      int row = v >> 2, off = (v & 3) * 8;
      *(uint4*)(&Bs[row * LDK + off]) =
          *(const uint4*)(&W[(size_t)(n0 + row) * K + kt + off]);
    }
    __syncthreads();
    const int ko = (lane >> 4) * 8;
    short8 af[WR], bfr[WC];
#pragma unroll
    for (int i = 0; i < WR; i++)
      af[i] = *(const short8*)(&As[(wm + i * 16 + (lane & 15)) * LDK + ko]);
#pragma unroll
    for (int j = 0; j < WC; j++)
      bfr[j] = *(const short8*)(&Bs[(wn + j * 16 + (lane & 15)) * LDK + ko]);
#pragma unroll
    for (int i = 0; i < WR; i++)
#pragma unroll
      for (int j = 0; j < WC; j++)
        acc[i][j] = __builtin_amdgcn_mfma_f32_16x16x32_bf16(bfr[j], af[i],
                                                            acc[i][j], 0, 0, 0);
    __syncthreads();
  }

#pragma unroll
  for (int i = 0; i < WR; i++) {
    int row = m0 + wm + i * 16 + (lane & 15);
#pragma unroll
    for (int j = 0; j < WC; j++) {
      int col = n0 + wn + j * 16 + ((lane >> 4) << 2);
      float bv[4] = {0.f, 0.f, 0.f, 0.f};
      if (bias) {
        float4 b4 = *(const float4*)&bias[col];
        bv[0] = b4.x; bv[1] = b4.y; bv[2] = b4.z; bv[3] = b4.w;
      }
      float v[4];
#pragma unroll
      for (int r = 0; r < 4; r++) {
        v[r] = acc[i][j][r] + bv[r];
        if (ACT == 1) v[r] = fast_gelu(v[r]);
        else if (ACT == 2) v[r] = 1.0f / (1.0f + __expf(-v[r]));
      }
      size_t idx = (size_t)row * N + col;
      if constexpr (std::is_same<OUTT, float>::value) {
        *(float4*)&C[idx] = make_float4(v[0], v[1], v[2], v[3]);
      } else {
        uint2 u;
        bf16* h = (bf16*)&u;
#pragma unroll
        for (int r = 0; r < 4; r++) h[r] = __float2bfloat16(v[r]);
        *(uint2*)&C[idx] = u;
      }
    }
  }
}

template <int BM, int BN, int ACT, typename OUTT>
__global__ __launch_bounds__(256) void gemm_bt(
    const bf16* __restrict__ A, const bf16* __restrict__ W,
    const float* __restrict__ bias, OUTT* __restrict__ C, int N, int K) {
  gemm_core<BM, BN, ACT, OUTT>(A, W, bias, C, N, K, blockIdx.x * BM,
                               blockIdx.y * BN);
}

// two independent E*E GEMMs in one launch (mha_out + do_out)
__global__ __launch_bounds__(256) void gemm_pair(
    const bf16* __restrict__ A0, const bf16* __restrict__ W0,
    const float* __restrict__ b0, bf16* __restrict__ C0,
    const bf16* __restrict__ A1, const bf16* __restrict__ W1,
    const float* __restrict__ b1, bf16* __restrict__ C1, int N, int K) {
  int nb = N >> 6;
  bool s = (int)blockIdx.y >= nb;
  gemm_core<128, 64, 0, bf16>(s ? A1 : A0, s ? W1 : W0, s ? b1 : b0,
                              s ? C1 : C0, N, K, blockIdx.x * 128,
                              (s ? (int)blockIdx.y - nb : (int)blockIdx.y) * 64);
}

// gate1: A is virtual concat [x | local_out | long_out] (K=1536), gelu act.
__global__ __launch_bounds__(256) void gemm_gate1(
    const bf16* __restrict__ x, const bf16* __restrict__ lo,
    const bf16* __restrict__ lg, const bf16* __restrict__ W,
    const float* __restrict__ bias, bf16* __restrict__ C) {
  constexpr int BM = 128, BN = 64, WR = 2, WC = 4;
  constexpr int N = 512, K = 1536;
  __shared__ bf16 As[BM * LDK];
  __shared__ bf16 Bs[BN * LDK];
  const int tid = threadIdx.x;
  const int lane = tid & 63;
  const int wid = tid >> 6;
  const int wm = wid * 32, wn = 0;
  const int m0 = blockIdx.x * BM, n0 = blockIdx.y * BN;

  floatx4 acc[WR][WC];
#pragma unroll
  for (int i = 0; i < WR; i++)
#pragma unroll
    for (int j = 0; j < WC; j++) acc[i][j] = (floatx4)0.0f;

  for (int kt = 0; kt < K; kt += BK) {
#pragma unroll
    for (int c = 0; c < 2; c++) {
      int v = c * 256 + tid;
      int row = v >> 2, off = (v & 3) * 8;
      int k = kt + off;
      const bf16* src = (k < 512) ? x : (k < 1024) ? lo : lg;
      int kk = k & 511;
      *(uint4*)(&As[row * LDK + off]) =
          *(const uint4*)(&src[(size_t)(m0 + row) * 512 + kk]);
    }
    {
      int v = tid;
      int row = v >> 2, off = (v & 3) * 8;
      *(uint4*)(&Bs[row * LDK + off]) =
          *(const uint4*)(&W[(size_t)(n0 + row) * K + kt + off]);
    }
    __syncthreads();
    const int ko = (lane >> 4) * 8;
    short8 af[WR], bfr[WC];
#pragma unroll
    for (int i = 0; i < WR; i++)
      af[i] = *(const short8*)(&As[(wm + i * 16 + (lane & 15)) * LDK + ko]);
#pragma unroll
    for (int j = 0; j < WC; j++)
      bfr[j] = *(const short8*)(&Bs[(wn + j * 16 + (lane & 15)) * LDK + ko]);
#pragma unroll
    for (int i = 0; i < WR; i++)
#pragma unroll
      for (int j = 0; j < WC; j++)
        acc[i][j] = __builtin_amdgcn_mfma_f32_16x16x32_bf16(bfr[j], af[i],
                                                            acc[i][j], 0, 0, 0);
    __syncthreads();
  }

#pragma unroll
  for (int i = 0; i < WR; i++) {
    int row = m0 + wm + i * 16 + (lane & 15);
#pragma unroll
    for (int j = 0; j < WC; j++) {
      int col = n0 + wn + j * 16 + ((lane >> 4) << 2);
      float4 b4 = *(const float4*)&bias[col];
      float bv[4] = {b4.x, b4.y, b4.z, b4.w};
      uint2 u;
      bf16* h = (bf16*)&u;
#pragma unroll
      for (int r = 0; r < 4; r++)
        h[r] = __float2bfloat16(fast_gelu(acc[i][j][r] + bv[r]));
      *(uint2*)&C[(size_t)row * N + col] = u;
    }
  }
}

// ---------------------------------------------- fused hi/lo triple GEMM
// C = Ah@Wh^T + Ah@Wl^T + Al@Wh^T + bias (fp32 out). Offset branch only.
template <int BM, int BN>
__global__ __launch_bounds__(256) void gemm3_bt(
    const bf16* __restrict__ Ah, const bf16* __restrict__ Al,
    const bf16* __restrict__ Wh, const bf16* __restrict__ Wl,
    const float* __restrict__ bias, float* __restrict__ C, int N, int K) {
  constexpr int WR = 2;
  constexpr int WC = (BM == 128) ? 4 : 2;
  __shared__ bf16 Ash[BM * LDK];
  __shared__ bf16 Asl[BM * LDK];
  __shared__ bf16 Bsh[BN * LDK];
  __shared__ bf16 Bsl[BN * LDK];
  const int tid = threadIdx.x;
  const int lane = tid & 63;
  const int wid = tid >> 6;
  int wm, wn;
  if constexpr (BM == 128) {
    wm = wid * 32; wn = 0;
  } else {
    wm = (wid >> 1) * 32; wn = (wid & 1) * 32;
  }
  const int m0 = blockIdx.x * BM, n0 = blockIdx.y * BN;

  floatx4 acc[WR][WC];
#pragma unroll
  for (int i = 0; i < WR; i++)
#pragma unroll
    for (int j = 0; j < WC; j++) acc[i][j] = (floatx4)0.0f;

  for (int kt = 0; kt < K; kt += BK) {
#pragma unroll
    for (int c = 0; c < BM / 64; c++) {
      int v = c * 256 + tid;
      int row = v >> 2, off = (v & 3) * 8;
      size_t g = (size_t)(m0 + row) * K + kt + off;
      *(uint4*)(&Ash[row * LDK + off]) = *(const uint4*)(&Ah[g]);
      *(uint4*)(&Asl[row * LDK + off]) = *(const uint4*)(&Al[g]);
    }
#pragma unroll
    for (int c = 0; c < BN / 64; c++) {
      int v = c * 256 + tid;
      int row = v >> 2, off = (v & 3) * 8;
      size_t g = (size_t)(n0 + row) * K + kt + off;
      *(uint4*)(&Bsh[row * LDK + off]) = *(const uint4*)(&Wh[g]);
      *(uint4*)(&Bsl[row * LDK + off]) = *(const uint4*)(&Wl[g]);
    }
    __syncthreads();
    const int ko = (lane >> 4) * 8;
    short8 ah[WR], al[WR], bh[WC], bl[WC];
#pragma unroll
    for (int i = 0; i < WR; i++) {
      int ro = (wm + i * 16 + (lane & 15)) * LDK + ko;
      ah[i] = *(const short8*)(&Ash[ro]);
      al[i] = *(const short8*)(&Asl[ro]);
    }
#pragma unroll
    for (int j = 0; j < WC; j++) {
      int ro = (wn + j * 16 + (lane & 15)) * LDK + ko;
      bh[j] = *(const short8*)(&Bsh[ro]);
      bl[j] = *(const short8*)(&Bsl[ro]);
    }
#pragma unroll
    for (int i = 0; i < WR; i++)
#pragma unroll
      for (int j = 0; j < WC; j++) {
        acc[i][j] = __builtin_amdgcn_mfma_f32_16x16x32_bf16(bh[j], ah[i],
                                                            acc[i][j], 0, 0, 0);
        acc[i][j] = __builtin_amdgcn_mfma_f32_16x16x32_bf16(bl[j], ah[i],
                                                            acc[i][j], 0, 0, 0);
        acc[i][j] = __builtin_amdgcn_mfma_f32_16x16x32_bf16(bh[j], al[i],
                                                            acc[i][j], 0, 0, 0);
      }
    __syncthreads();
  }

#pragma unroll
  for (int i = 0; i < WR; i++) {
    int row = m0 + wm + i * 16 + (lane & 15);
#pragma unroll
    for (int j = 0; j < WC; j++) {
      int col = n0 + wn + j * 16 + ((lane >> 4) << 2);
      float4 b4 = *(const float4*)&bias[col];
      float bv[4] = {b4.x, b4.y, b4.z, b4.w};
      float v[4];
#pragma unroll
      for (int r = 0; r < 4; r++) v[r] = acc[i][j][r] + bv[r];
      *(float4*)&C[(size_t)row * N + col] = make_float4(v[0], v[1], v[2], v[3]);
    }
  }
}

// ------------------------------------------------------- local attention
// qkv_all row stride 3072: [q 0:512 | k 512:1024 | v 1024:1536 | qd|kd|vd]
__global__ __launch_bounds__(256) void local_attn_kernel(
    const bf16* __restrict__ qkv, const void* __restrict__ pm,
    const int* __restrict__ meta, bf16* __restrict__ lo) {
  int lane = threadIdx.x & 63;
  int t = blockIdx.x * 4 + (threadIdx.x >> 6);
  int b = t >> 10, s = t & 1023;
  int h = lane >> 3, sub = lane & 7;
  int flag = meta[0];
  float q[8];
  load8f(qkv + (size_t)t * 3072 + h * 64 + sub * 8, q);
  float sc[4];
  bool val[4];
#pragma unroll
  for (int w = 0; w < 4; w++) {
    int kp = s - 3 + w;
    bool v = (kp >= 0) && !is_pad(pm, flag, b * kS + kp);
    float d = 0.0f;
    if (v) {
      float kk[8];
      load8f(qkv + (size_t)(b * kS + kp) * 3072 + 512 + h * 64 + sub * 8, kk);
#pragma unroll
      for (int e = 0; e < 8; e++) d += q[e] * kk[e];
    }
    d += __shfl_xor(d, 1);
    d += __shfl_xor(d, 2);
    d += __shfl_xor(d, 4);
    sc[w] = v ? d / 8.0f : -INFINITY;
    val[w] = v;
  }
  float mx = fmaxf(fmaxf(sc[0], sc[1]), fmaxf(sc[2], sc[3]));
  float a[4] = {0.f, 0.f, 0.f, 0.f};
  if (mx != -INFINITY) {
    float ssum = 0.f;
#pragma unroll
    for (int w = 0; w < 4; w++) {
      float e = val[w] ? expf(sc[w] - mx) : 0.0f;
      a[w] = e;
      ssum += e;
    }
#pragma unroll
    for (int w = 0; w < 4; w++) a[w] /= ssum;
  }
  float o[8] = {0.f, 0.f, 0.f, 0.f, 0.f, 0.f, 0.f, 0.f};
#pragma unroll
  for (int w = 0; w < 4; w++) {
    if (val[w] && a[w] > 0.0f) {
      int kp = s - 3 + w;
      float vv[8];
      load8f(qkv + (size_t)(b * kS + kp) * 3072 + 1024 + h * 64 + sub * 8, vv);
#pragma unroll
      for (int e = 0; e < 8; e++) o[e] += a[w] * vv[e];
    }
  }
  store8b(lo + (size_t)t * kE + lane * 8, o);
}

// ------------------------------------------- fp32 -> gelu -> bf16 hi/lo
__global__ __launch_bounds__(256) void gelu_split_kernel(
    const float* __restrict__ S, bf16* __restrict__ hi, bf16* __restrict__ lo) {
  int i = (blockIdx.x * 256 + threadIdx.x) * 4;
#pragma unroll
  for (int c = 0; c < 4; c++) {
    float v = S[i + c];
    float g = 0.5f * v * (1.0f + erff(v * 0.70710678118654752f));
    bf16 a = __float2bfloat16(g);
    hi[i + c] = a;
    lo[i + c] = __float2bfloat16(g - __bfloat162float(a));
  }
}

// ----------------------------------------------------------- sampler
__global__ __launch_bounds__(256) void sampler_kernel(
    const float* __restrict__ rawf, const void* __restrict__ pm,
    const int* __restrict__ meta, int* __restrict__ sp,
    unsigned int* __restrict__ invm) {
  int t = blockIdx.x * 8 + (threadIdx.x >> 5);
  int p = threadIdx.x & 31;
  int b = t >> 10, s = t & 1023;
  int flag = meta[0];
  float off = 0.0f;
#pragma unroll
  for (int h = 0; h < kH; h++) off += tanhf(rawf[(size_t)t * 256 + h * kP + p]);
  double anchor = 0.1 + 0.8 * (double)p / 31.0;
  double sampled = anchor * (double)s + (double)off;
  double lov = fmax(0.0, (double)s - 256.0);
  sampled = fmin(fmax(sampled, lov), (double)s);
  int vlen = meta[1 + b];
  sampled = fmin(sampled, (double)(vlen - 1));
  int spv = (int)rint(sampled);
  bool inv = is_pad(pm, flag, b * kS + spv) || (spv > s) ||
             (spv >= max(0, s - 3));
  sp[(size_t)t * kP + p] = spv;
  unsigned long long m = __ballot(inv);
  int lane = threadIdx.x & 63;
  if (lane == 0) invm[t] = (unsigned int)m;
  if (lane == 32) invm[t] = (unsigned int)(m >> 32);
}

// ------------------------------------------------------ long attention
// qkv_all: qd at +1536, kd at +2048, vd at +2560 (stride 3072).
__global__ __launch_bounds__(256) void long_attn_kernel(
    const bf16* __restrict__ qkv, const int* __restrict__ sp,
    const unsigned int* __restrict__ invm, bf16* __restrict__ ctx) {
  int lane = threadIdx.x & 63;
  int bid = blockIdx.x;
  int sbid = (bid & 7) * 256 + (bid >> 3);  // XCD-contiguous token ranges
  int t = sbid * 4 + (threadIdx.x >> 6);
  int b = t >> 10;
  int p = lane & 31;
  int row_abs = b * kS + sp[(size_t)t * kP + p];
  float q[8];
  load8f(qkv + (size_t)t * 3072 + 1536 + lane * 8, q);
  float sc_mine = 0.0f;
#pragma unroll 4
  for (int pp = 0; pp < 32; pp++) {
    int row = __shfl(row_abs, pp);
    float kk[8];
    load8f(qkv + (size_t)row * 3072 + 2048 + lane * 8, kk);
    float d = 0.0f;
#pragma unroll
    for (int e = 0; e < 8; e++) d += q[e] * kk[e];
#pragma unroll
    for (int m = 1; m < 64; m <<= 1) d += __shfl_xor(d, m);
    if (p == pp) sc_mine = d;
  }
  bool inv = (invm[t] >> p) & 1u;
  float sc = inv ? -INFINITY : sc_mine / 22.627416997969522f;  // sqrt(512)
  float mx = sc;
#pragma unroll
  for (int m = 1; m < 32; m <<= 1) mx = fmaxf(mx, __shfl_xor(mx, m));
  float e = (inv || mx == -INFINITY) ? 0.0f : expf(sc - mx);
  float ssum = e;
#pragma unroll
  for (int m = 1; m < 32; m <<= 1) ssum += __shfl_xor(ssum, m);
  float a = (ssum > 0.0f) ? e / ssum : 0.0f;
  float o[8] = {0.f, 0.f, 0.f, 0.f, 0.f, 0.f, 0.f, 0.f};
#pragma unroll 4
  for (int pp = 0; pp < 32; pp++) {
    float ap = __shfl(a, pp);
    int row = __shfl(row_abs, pp);
    if (ap != 0.0f) {
      float vv[8];
      load8f(qkv + (size_t)row * 3072 + 2560 + lane * 8, vv);
#pragma unroll
      for (int e2 = 0; e2 < 8; e2++) o[e2] += ap * vv[e2];
    }
  }
  store8b(ctx + (size_t)t * kE + lane * 8, o);
}

// ------------------------------------------------------------------- LN1
__global__ __launch_bounds__(256) void ln1_kernel(
    const void* __restrict__ xin, const int* __restrict__ meta,
    const bf16* __restrict__ lo, const bf16* __restrict__ lg,
    const bf16* __restrict__ g, const float* __restrict__ gamma,
    const float* __restrict__ beta, bf16* __restrict__ x1b,
    float* __restrict__ x1f) {
  int lane = threadIdx.x & 63;
  int t = blockIdx.x * 4 + (threadIdx.x >> 6);
  size_t base = (size_t)t * kE + lane * 8;
  float xv[8], lov[8], lgv[8], gv[8], h[8];
  if (meta[9]) {
    const float4* xf = (const float4*)((const float*)xin + base);
    float4 a = xf[0], b2 = xf[1];
    xv[0] = a.x; xv[1] = a.y; xv[2] = a.z; xv[3] = a.w;
    xv[4] = b2.x; xv[5] = b2.y; xv[6] = b2.z; xv[7] = b2.w;
  } else {
    load8f((const bf16*)xin + base, xv);
  }
  load8f(lo + base, lov);
  load8f(lg + base, lgv);
  load8f(g + base, gv);
  float s1 = 0.f, s2 = 0.f;
#pragma unroll
  for (int e = 0; e < 8; e++) {
    h[e] = xv[e] + gv[e] * lov[e] + (1.0f - gv[e]) * lgv[e];
    s1 += h[e];
    s2 += h[e] * h[e];
  }
#pragma unroll
  for (int m = 1; m < 64; m <<= 1) {
    s1 += __shfl_xor(s1, m);
    s2 += __shfl_xor(s2, m);
  }
  float mean = s1 * (1.0f / kE);
  float var = s2 * (1.0f / kE) - mean * mean;
  float rstd = 1.0f / sqrtf(var + 1e-5f);
  float y[8];
#pragma unroll
  for (int e = 0; e < 8; e++)
    y[e] = (h[e] - mean) * rstd * gamma[lane * 8 + e] + beta[lane * 8 + e];
  store8b(x1b + base, y);
#pragma unroll
  for (int e = 0; e < 8; e++) x1f[base + e] = y[e];
}

// ------------------------------------------------------------------- LN2
__global__ __launch_bounds__(256) void ln2_kernel(
    const float* __restrict__ x1f, const float* __restrict__ ff,
    const float* __restrict__ gamma, const float* __restrict__ beta,
    const int* __restrict__ meta, void* __restrict__ out) {
  int lane = threadIdx.x & 63;
  int t = blockIdx.x * 4 + (threadIdx.x >> 6);
  size_t base = (size_t)t * kE + lane * 8;
  float h[8];
  float s1 = 0.f, s2 = 0.f;
#pragma unroll
  for (int e = 0; e < 8; e++) {
    h[e] = x1f[base + e] + ff[base + e];
    s1 += h[e];
    s2 += h[e] * h[e];
  }
#pragma unroll
  for (int m = 1; m < 64; m <<= 1) {
    s1 += __shfl_xor(s1, m);
    s2 += __shfl_xor(s2, m);
  }
  float mean = s1 * (1.0f / kE);
  float var = s2 * (1.0f / kE) - mean * mean;
  float rstd = 1.0f / sqrtf(var + 1e-5f);
  float y[8];
#pragma unroll
  for (int e = 0; e < 8; e++)
    y[e] = (h[e] - mean) * rstd * gamma[lane * 8 + e] + beta[lane * 8 + e];
  if (meta[9]) {
    float* of = (float*)out + base;
    ((float4*)of)[0] = make_float4(y[0], y[1], y[2], y[3]);
    ((float4*)of)[1] = make_float4(y[4], y[5], y[6], y[7]);
  } else {
    store8b((bf16*)out + base, y);
  }
}

// ------------------------------------------------------------------ launch
extern "C" void kernel_launch(void* const* d_in, const int* in_sizes, int n_in,
                              void* d_out, int out_size, void* d_ws,
                              size_t ws_size, hipStream_t stream) {
  const void* x = d_in[0];
  const void* pm = d_in[1];

  char* w = (char*)d_ws;
  auto alloc = [&](size_t bytes) {
    char* p = w;
    w += (bytes + 255) & ~(size_t)255;
    return p;
  };
  // qkv_all[8192][3072]: q|k|v|qd|kd|vd. After long_attn it is dead and its
  // 50.3MB region is recycled: front 16.8MB = f_f32 (ffn2 out), rest 33.5MB
  // = ffn hidden.
  bf16* qkv_all = (bf16*)alloc((size_t)kTok * 3072 * 2);
  bf16* lo_ctx = (bf16*)alloc((size_t)kTok * kE * 2);
  bf16* ctx2 = (bf16*)alloc((size_t)kTok * kE * 2);
  bf16* local_out = (bf16*)alloc((size_t)kTok * kE * 2);
  bf16* long_out = (bf16*)alloc((size_t)kTok * kE * 2);
  bf16* hbuf = (bf16*)alloc((size_t)kTok * kE * 2);    // h_hi / gate hidden
  bf16* gbuf = (bf16*)alloc((size_t)kTok * kE * 2);    // gate out
  bf16* x1b = (bf16*)alloc((size_t)kTok * kE * 2);     // h_lo / x1 bf16
  float* x1f = (float*)alloc((size_t)kTok * kE * 4);   // S32 / x1 fp32
  float* rawf = (float*)alloc((size_t)kTok * 256 * 4);
  int* sp = (int*)alloc((size_t)kTok * kP * 4);
  unsigned int* invm = (unsigned int*)alloc((size_t)kTok * 4);
  int* meta = (int*)alloc(256);
  bf16* x_hi = (bf16*)alloc((size_t)kTok * kE * 2);
  bf16* x_lo = (bf16*)alloc((size_t)kTok * kE * 2);
  bf16* wall = (bf16*)alloc((size_t)3072 * 512 * 2);  // ip|dq|dk|dv weights
  bf16* mow = (bf16*)alloc(512 * 512 * 2);
  bf16* dow = (bf16*)alloc(512 * 512 * 2);
  bf16* o1h = (bf16*)alloc(512 * 512 * 2);
  bf16* o1l = (bf16*)alloc(512 * 512 * 2);
  bf16* o2h = (bf16*)alloc(256 * 512 * 2);
  bf16* o2l = (bf16*)alloc(256 * 512 * 2);
  bf16* g1w = (bf16*)alloc(512 * 1536 * 2);
  bf16* g2w = (bf16*)alloc(512 * 512 * 2);
  bf16* f1w = (bf16*)alloc((size_t)2048 * 512 * 2);
  bf16* f2w = (bf16*)alloc((size_t)512 * 2048 * 2);
  float* ball = (float*)alloc(3072 * 4);
  float* mob = (float*)alloc(512 * 4);
  float* dob = (float*)alloc(512 * 4);
  float* o1b = (float*)alloc(512 * 4);
  float* o2b = (float*)alloc(256 * 4);
  float* g1b = (float*)alloc(512 * 4);
  float* g2b = (float*)alloc(512 * 4);
  float* n1g = (float*)alloc(512 * 4);
  float* n1bt = (float*)alloc(512 * 4);
  float* n2g = (float*)alloc(512 * 4);
  float* n2bt = (float*)alloc(512 * 4);
  float* f1b = (float*)alloc(2048 * 4);
  float* f2b = (float*)alloc(512 * 4);

  float* S32 = x1f;            // off1 fp32 out (dead before LN1)
  bf16* h_hi = hbuf;
  bf16* h_lo = x1b;
  float* f_f32 = (float*)qkv_all;                       // 16.8MB
  bf16* ffn_h = (bf16*)((char*)qkv_all + (size_t)kTok * kE * 4);  // 33.5MB

  dim3 blk(256);
  detect_kernel<<<1, blk, 0, stream>>>(x, meta);
  meta_kernel<<<1, blk, 0, stream>>>(pm, meta);

  // ---- batched ingest (2 launches)
  CvtJobs J;
  auto job = [](const void* s, bf16* hi, bf16* lo, int n) {
    CvtJob j; j.src = s; j.hi = hi; j.lo = lo; j.nblk = n >> 10; return j;
  };
  J.j[0] = job(d_in[0], x_hi, x_lo, kTok * kE);
  J.j[1] = job(d_in[2], wall, nullptr, 1536 * 512);
  J.j[2] = job(d_in[6], wall + (size_t)1536 * 512, nullptr, 512 * 512);
  J.j[3] = job(d_in[8], wall + (size_t)2048 * 512, nullptr, 512 * 512);
  J.j[4] = job(d_in[10], wall + (size_t)2560 * 512, nullptr, 512 * 512);
  J.j[5] = job(d_in[4], mow, nullptr, 512 * 512);
  J.j[6] = job(d_in[12], dow, nullptr, 512 * 512);
  J.j[7] = job(d_in[14], o1h, o1l, 512 * 512);
  J.j[8] = job(d_in[16], o2h, o2l, 256 * 512);
  J.j[9] = job(d_in[18], g1w, nullptr, 512 * 1536);
  J.j[10] = job(d_in[20], g2w, nullptr, 512 * 512);
  J.j[11] = job(d_in[26], f1w, nullptr, 2048 * 512);
  J.j[12] = job(d_in[28], f2w, nullptr, 512 * 2048);
  int totblk = 0;
  for (int i = 0; i < 13; i++) totblk += J.j[i].nblk;
  cvt_all_kernel<<<totblk, blk, 0, stream>>>(J, meta);

  CvtFJobs JF;
  auto fjob = [](const void* s, float* d, int n) {
    CvtFJob j; j.src = s; j.dst = d; j.n = n; return j;
  };
  JF.j[0] = fjob(d_in[3], ball, 1536);
  JF.j[1] = fjob(d_in[7], ball + 1536, 512);
  JF.j[2] = fjob(d_in[9], ball + 2048, 512);
  JF.j[3] = fjob(d_in[11], ball + 2560, 512);
  JF.j[4] = fjob(d_in[5], mob, 512);
  JF.j[5] = fjob(d_in[13], dob, 512);
  JF.j[6] = fjob(d_in[15], o1b, 512);
  JF.j[7] = fjob(d_in[17], o2b, 256);
  JF.j[8] = fjob(d_in[19], g1b, 512);
  JF.j[9] = fjob(d_in[21], g2b, 512);
  JF.j[10] = fjob(d_in[22], n1g, 512);
  JF.j[11] = fjob(d_in[23], n1bt, 512);
  JF.j[12] = fjob(d_in[24], n2g, 512);
  JF.j[13] = fjob(d_in[25], n2bt, 512);
  JF.j[14] = fjob(d_in[27], f1b, 2048);
  JF.j[15] = fjob(d_in[29], f2b, 512);
  cvt_small_kernel<<<1, blk, 0, stream>>>(JF, meta);

  // ---- merged qkv + deformable-qkv projection (N=3072)
  gemm_bt<128, 128, 0, bf16><<<dim3(64, 24), blk, 0, stream>>>(
      x_hi, wall, ball, qkv_all, 3072, kE);
  // ---- offset branch (fused hi/lo triples; exact-erff path)
  gemm3_bt<128, 64><<<dim3(64, 8), blk, 0, stream>>>(
      x_hi, x_lo, o1h, o1l, o1b, S32, kE, kE);
  local_attn_kernel<<<2048, blk, 0, stream>>>(qkv_all, pm, meta, lo_ctx);
  gelu_split_kernel<<<4096, blk, 0, stream>>>(S32, h_hi, h_lo);
  gemm3_bt<64, 64><<<dim3(128, 4), blk, 0, stream>>>(
      h_hi, h_lo, o2h, o2l, o2b, rawf, 256, kE);
  sampler_kernel<<<1024, blk, 0, stream>>>(rawf, pm, meta, sp, invm);
  long_attn_kernel<<<2048, blk, 0, stream>>>(qkv_all, sp, invm, ctx2);

  // ---- both attention output projections in one launch
  gemm_pair<<<dim3(64, 16), blk, 0, stream>>>(lo_ctx, mow, mob, local_out,
                                              ctx2, dow, dob, long_out, kE, kE);

  // ---- gate (virtual concat in gate1 staging)
  gemm_gate1<<<dim3(64, 8), blk, 0, stream>>>(x_hi, local_out, long_out, g1w,
                                              g1b, hbuf);
  gemm_bt<128, 64, 2, bf16><<<dim3(64, 8), blk, 0, stream>>>(
      hbuf, g2w, g2b, gbuf, kE, kE);

  // ---- fuse + LN1 + FFN + LN2
  ln1_kernel<<<2048, blk, 0, stream>>>(x, meta, local_out, long_out, gbuf, n1g,
                                       n1bt, x1b, x1f);
  gemm_bt<128, 128, 1, bf16><<<dim3(64, 16), blk, 0, stream>>>(
      x1b, f1w, f1b, ffn_h, kHid, kE);
  gemm_bt<128, 64, 0, float><<<dim3(64, 8), blk, 0, stream>>>(
      ffn_h, f2w, f2b, f_f32, kE, kHid);
  ln2_kernel<<<2048, blk, 0, stream>>>(x1f, f_f32, n2g, n2bt, meta, d_out);
}

// Round 5
// 477.075 us; speedup vs baseline: 1.5693x; 1.0266x over previous
//
#include <hip/hip_runtime.h>
#include <hip/hip_bf16.h>
#include <type_traits>

typedef __hip_bfloat16 bf16;
typedef __attribute__((ext_vector_type(8))) short short8;
typedef __attribute__((ext_vector_type(4))) float floatx4;

static constexpr int kB = 8;
static constexpr int kS = 1024;
static constexpr int kE = 512;
static constexpr int kH = 8;
static constexpr int kP = 32;
static constexpr int kTok = kB * kS;   // 8192
static constexpr int kHid = 2048;

// meta layout: [0]=pm int32 flag, [1..8]=valid_len, [9]=inputs-are-fp32 flag
// ---------------------------------------------------------------- helpers
__device__ __forceinline__ void load8f(const bf16* p, float* f) {
  uint4 u = *(const uint4*)p;
  const bf16* h = (const bf16*)&u;
#pragma unroll
  for (int e = 0; e < 8; e++) f[e] = __bfloat162float(h[e]);
}
__device__ __forceinline__ void store8b(bf16* p, const float* f) {
  uint4 u;
  bf16* h = (bf16*)&u;
#pragma unroll
  for (int e = 0; e < 8; e++) h[e] = __float2bfloat16(f[e]);
  *(uint4*)p = u;
}
__device__ __forceinline__ bool is_pad(const void* pm, int flag, int idx) {
  return flag ? (((const int*)pm)[idx] != 0)
              : (((const unsigned char*)pm)[idx] != 0);
}
__device__ __forceinline__ float fast_gelu(float x) {
  float u = x * (0.7978845608f + 0.044714998f * x * x);
  float e = __expf(2.0f * u);
  float t = 1.0f - 2.0f / (e + 1.0f);
  return 0.5f * x * (1.0f + t);
}
// async global->LDS 16B DMA. dest = wave-uniform lds base + lane*16.
__device__ __forceinline__ void dma16(const bf16* g, bf16* l) {
  __builtin_amdgcn_global_load_lds(
      (const __attribute__((address_space(1))) unsigned int*)g,
      (__attribute__((address_space(3))) unsigned int*)l, 16, 0, 0);
}

// -------------------------------------------------------- dtype detection
__global__ __launch_bounds__(256) void detect_kernel(const void* __restrict__ x,
                                                     int* __restrict__ meta) {
  __shared__ int cnt;
  if (threadIdx.x == 0) cnt = 0;
  __syncthreads();
  const unsigned short* u = (const unsigned short*)x;
  int c = 0;
  for (int i = threadIdx.x; i < 1024; i += 256) {
    int e = (u[i] >> 7) & 0xFF;
    if (e >= 0x90) c++;
  }
  if (c) atomicAdd(&cnt, c);
  __syncthreads();
  if (threadIdx.x == 0) meta[9] = (cnt > 64) ? 1 : 0;
}

// ------------------------------------------------------------- meta kernel
__global__ __launch_bounds__(256) void meta_kernel(const void* __restrict__ pm,
                                                   int* __restrict__ meta) {
  __shared__ int bigfound;
  __shared__ int cnt[kB];
  int tid = threadIdx.x;
  if (tid == 0) bigfound = 0;
  if (tid < kB) cnt[tid] = 0;
  __syncthreads();
  const unsigned int* w = (const unsigned int*)pm;
  int f = 0;
  for (int i = tid; i < 2048; i += 256)
    if (w[i] & 0xFFFFFFFEu) f = 1;
  if (f) atomicOr(&bigfound, 1);
  __syncthreads();
  int flag = bigfound ? 0 : 1;
  for (int i = tid; i < kTok; i += 256) {
    if (is_pad(pm, flag, i)) atomicAdd(&cnt[i >> 10], 1);
  }
  __syncthreads();
  if (tid == 0) meta[0] = flag;
  if (tid < kB) {
    int vl = kS - cnt[tid];
    if (vl < 1) vl = 1;
    meta[1 + tid] = vl;
  }
}

// ------------------------------------------- batched ingest (one launch)
struct CvtJob { const void* src; bf16* hi; bf16* lo; int nblk; };
struct CvtJobs { CvtJob j[13]; };
__global__ __launch_bounds__(256) void cvt_all_kernel(CvtJobs jobs,
                                                      const int* __restrict__ meta) {
  int fp = meta[9];
  int b = blockIdx.x, ji = 0;
  while (b >= jobs.j[ji].nblk) { b -= jobs.j[ji].nblk; ji++; }
  CvtJob J = jobs.j[ji];
  int i = b * 1024 + threadIdx.x * 4;
  float v[4];
  if (fp) {
    float4 f = ((const float4*)J.src)[i >> 2];
    v[0] = f.x; v[1] = f.y; v[2] = f.z; v[3] = f.w;
  } else {
    uint2 u = *(const uint2*)((const bf16*)J.src + i);
    const bf16* h = (const bf16*)&u;
#pragma unroll
    for (int e = 0; e < 4; e++) v[e] = __bfloat162float(h[e]);
  }
  uint2 uh;
  bf16* hh = (bf16*)&uh;
#pragma unroll
  for (int e = 0; e < 4; e++) hh[e] = __float2bfloat16(v[e]);
  *(uint2*)(J.hi + i) = uh;
  if (J.lo) {
    uint2 ul;
    bf16* hl = (bf16*)&ul;
#pragma unroll
    for (int e = 0; e < 4; e++)
      hl[e] = __float2bfloat16(v[e] - __bfloat162float(hh[e]));
    *(uint2*)(J.lo + i) = ul;
  }
}

struct CvtFJob { const void* src; float* dst; int n; };
struct CvtFJobs { CvtFJob j[16]; };
__global__ __launch_bounds__(256) void cvt_small_kernel(CvtFJobs jobs,
                                                        const int* __restrict__ meta) {
  int fp = meta[9];
#pragma unroll 1
  for (int ji = 0; ji < 16; ji++) {
    CvtFJob J = jobs.j[ji];
    for (int i = threadIdx.x; i < J.n; i += 256)
      J.dst[i] = fp ? ((const float*)J.src)[i]
                    : __bfloat162float(((const bf16*)J.src)[i]);
  }
}

// ------------------------------------------------------------- GEMM core
// C[M,N] = act(A[M,K] @ W[N,K]^T + bias). Staging = global_load_lds dwordx4.
// LDS rows are UNPADDED 64B (BK=32 bf16); 16B-chunk slot sigma of row r holds
// global chunk sigma ^ ((r>>1)&3)  -> conflict-free ds_read_b128 (2-way max).
// mfma operands swapped: lane's 4 acc regs = 4 consecutive N-cols.
static constexpr int BK = 32;

template <int BM, int BN, int ACT, typename OUTT>
__device__ __forceinline__ void gemm_core(const bf16* __restrict__ A,
                                          const bf16* __restrict__ W,
                                          const float* __restrict__ bias,
                                          OUTT* __restrict__ C, int N, int K,
                                          int m0, int n0) {
  constexpr int WR = (BM == 128 && BN == 128) ? 4 : 2;
  constexpr int WC = 4;
  __shared__ bf16 As[BM * BK];
  __shared__ bf16 Bs[BN * BK];
  const int tid = threadIdx.x;
  const int lane = tid & 63;
  const int wid = tid >> 6;
  int wm, wn;
  if constexpr (BM == 128 && BN == 128) {
    wm = (wid >> 1) * 64; wn = (wid & 1) * 64;
  } else {  // 128x64
    wm = wid * 32; wn = 0;
  }

  floatx4 acc[WR][WC];
#pragma unroll
  for (int i = 0; i < WR; i++)
#pragma unroll
    for (int j = 0; j < WC; j++) acc[i][j] = (floatx4)0.0f;

  for (int kt = 0; kt < K; kt += BK) {
#pragma unroll
    for (int c = 0; c < BM / 64; c++) {
      int seg = c * 64 + wid * 16;
      int row = seg + (lane >> 2);
      int ch = (lane & 3) ^ ((row >> 1) & 3);
      dma16(&A[(size_t)(m0 + row) * K + kt + ch * 8], &As[seg * BK]);
    }
#pragma unroll
    for (int c = 0; c < BN / 64; c++) {
      int seg = c * 64 + wid * 16;
      int row = seg + (lane >> 2);
      int ch = (lane & 3) ^ ((row >> 1) & 3);
      dma16(&W[(size_t)(n0 + row) * K + kt + ch * 8], &Bs[seg * BK]);
    }
    __syncthreads();
    const int kb = lane >> 4;
    short8 af[WR], bfr[WC];
#pragma unroll
    for (int i = 0; i < WR; i++) {
      int r = wm + i * 16 + (lane & 15);
      af[i] = *(const short8*)(&As[r * BK + ((kb ^ ((r >> 1) & 3)) << 3)]);
    }
#pragma unroll
    for (int j = 0; j < WC; j++) {
      int r = wn + j * 16 + (lane & 15);
      bfr[j] = *(const short8*)(&Bs[r * BK + ((kb ^ ((r >> 1) & 3)) << 3)]);
    }
#pragma unroll
    for (int i = 0; i < WR; i++)
#pragma unroll
      for (int j = 0; j < WC; j++)
        acc[i][j] = __builtin_amdgcn_mfma_f32_16x16x32_bf16(bfr[j], af[i],
                                                            acc[i][j], 0, 0, 0);
    __syncthreads();
  }

#pragma unroll
  for (int i = 0; i < WR; i++) {
    int row = m0 + wm + i * 16 + (lane & 15);
#pragma unroll
    for (int j = 0; j < WC; j++) {
      int col = n0 + wn + j * 16 + ((lane >> 4) << 2);
      float bv[4] = {0.f, 0.f, 0.f, 0.f};
      if (bias) {
        float4 b4 = *(const float4*)&bias[col];
        bv[0] = b4.x; bv[1] = b4.y; bv[2] = b4.z; bv[3] = b4.w;
      }
      float v[4];
#pragma unroll
      for (int r = 0; r < 4; r++) {
        v[r] = acc[i][j][r] + bv[r];
        if (ACT == 1) v[r] = fast_gelu(v[r]);
        else if (ACT == 2) v[r] = 1.0f / (1.0f + __expf(-v[r]));
      }
      size_t idx = (size_t)row * N + col;
      if constexpr (std::is_same<OUTT, float>::value) {
        *(float4*)&C[idx] = make_float4(v[0], v[1], v[2], v[3]);
      } else {
        uint2 u;
        bf16* h = (bf16*)&u;
#pragma unroll
        for (int r = 0; r < 4; r++) h[r] = __float2bfloat16(v[r]);
        *(uint2*)&C[idx] = u;
      }
    }
  }
}

template <int BM, int BN, int ACT, typename OUTT>
__global__ __launch_bounds__(256) void gemm_bt(
    const bf16* __restrict__ A, const bf16* __restrict__ W,
    const float* __restrict__ bias, OUTT* __restrict__ C, int N, int K) {
  gemm_core<BM, BN, ACT, OUTT>(A, W, bias, C, N, K, blockIdx.x * BM,
                               blockIdx.y * BN);
}

// two independent E*E GEMMs in one launch (mha_out + do_out)
__global__ __launch_bounds__(256) void gemm_pair(
    const bf16* __restrict__ A0, const bf16* __restrict__ W0,
    const float* __restrict__ b0, bf16* __restrict__ C0,
    const bf16* __restrict__ A1, const bf16* __restrict__ W1,
    const float* __restrict__ b1, bf16* __restrict__ C1, int N, int K) {
  int nb = N >> 6;
  bool s = (int)blockIdx.y >= nb;
  gemm_core<128, 64, 0, bf16>(s ? A1 : A0, s ? W1 : W0, s ? b1 : b0,
                              s ? C1 : C0, N, K, blockIdx.x * 128,
                              (s ? (int)blockIdx.y - nb : (int)blockIdx.y) * 64);
}

// gate1: A is virtual concat [x | local_out | long_out] (K=1536), gelu act.
__global__ __launch_bounds__(256) void gemm_gate1(
    const bf16* __restrict__ x, const bf16* __restrict__ lo,
    const bf16* __restrict__ lg, const bf16* __restrict__ W,
    const float* __restrict__ bias, bf16* __restrict__ C) {
  constexpr int BM = 128, BN = 64, WR = 2, WC = 4;
  constexpr int N = 512, K = 1536;
  __shared__ bf16 As[BM * BK];
  __shared__ bf16 Bs[BN * BK];
  const int tid = threadIdx.x;
  const int lane = tid & 63;
  const int wid = tid >> 6;
  const int wm = wid * 32, wn = 0;
  const int m0 = blockIdx.x * BM, n0 = blockIdx.y * BN;

  floatx4 acc[WR][WC];
#pragma unroll
  for (int i = 0; i < WR; i++)
#pragma unroll
    for (int j = 0; j < WC; j++) acc[i][j] = (floatx4)0.0f;

  for (int kt = 0; kt < K; kt += BK) {
    const bf16* src = (kt < 512) ? x : (kt < 1024) ? lo : lg;
    int kk = kt & 511;
#pragma unroll
    for (int c = 0; c < 2; c++) {
      int seg = c * 64 + wid * 16;
      int row = seg + (lane >> 2);
      int ch = (lane & 3) ^ ((row >> 1) & 3);
      dma16(&src[(size_t)(m0 + row) * 512 + kk + ch * 8], &As[seg * BK]);
    }
    {
      int seg = wid * 16;
      int row = seg + (lane >> 2);
      int ch = (lane & 3) ^ ((row >> 1) & 3);
      dma16(&W[(size_t)(n0 + row) * K + kt + ch * 8], &Bs[seg * BK]);
    }
    __syncthreads();
    const int kb = lane >> 4;
    short8 af[WR], bfr[WC];
#pragma unroll
    for (int i = 0; i < WR; i++) {
      int r = wm + i * 16 + (lane & 15);
      af[i] = *(const short8*)(&As[r * BK + ((kb ^ ((r >> 1) & 3)) << 3)]);
    }
#pragma unroll
    for (int j = 0; j < WC; j++) {
      int r = wn + j * 16 + (lane & 15);
      bfr[j] = *(const short8*)(&Bs[r * BK + ((kb ^ ((r >> 1) & 3)) << 3)]);
    }
#pragma unroll
    for (int i = 0; i < WR; i++)
#pragma unroll
      for (int j = 0; j < WC; j++)
        acc[i][j] = __builtin_amdgcn_mfma_f32_16x16x32_bf16(bfr[j], af[i],
                                                            acc[i][j], 0, 0, 0);
    __syncthreads();
  }

#pragma unroll
  for (int i = 0; i < WR; i++) {
    int row = m0 + wm + i * 16 + (lane & 15);
#pragma unroll
    for (int j = 0; j < WC; j++) {
      int col = n0 + wn + j * 16 + ((lane >> 4) << 2);
      float4 b4 = *(const float4*)&bias[col];
      float bv[4] = {b4.x, b4.y, b4.z, b4.w};
      uint2 u;
      bf16* h = (bf16*)&u;
#pragma unroll
      for (int r = 0; r < 4; r++)
        h[r] = __float2bfloat16(fast_gelu(acc[i][j][r] + bv[r]));
      *(uint2*)&C[(size_t)row * N + col] = u;
    }
  }
}

// ---------------------------------------------- fused hi/lo triple GEMM
// acc = Ah@Wh^T + Ah@Wl^T + Al@Wh^T + bias. Offset branch (index-critical).
// SPLIT: epilogue applies exact gelu and writes bf16 hi/lo pair.
template <int BM, int BN, bool SPLIT>
__global__ __launch_bounds__(256) void gemm3_bt(
    const bf16* __restrict__ Ah, const bf16* __restrict__ Al,
    const bf16* __restrict__ Wh, const bf16* __restrict__ Wl,
    const float* __restrict__ bias, float* __restrict__ Cf,
    bf16* __restrict__ Chi, bf16* __restrict__ Clo, int N, int K) {
  constexpr int WR = 2;
  constexpr int WC = (BM == 128) ? 4 : 2;
  __shared__ bf16 Ash[BM * BK];
  __shared__ bf16 Asl[BM * BK];
  __shared__ bf16 Bsh[BN * BK];
  __shared__ bf16 Bsl[BN * BK];
  const int tid = threadIdx.x;
  const int lane = tid & 63;
  const int wid = tid >> 6;
  int wm, wn;
  if constexpr (BM == 128) {
    wm = wid * 32; wn = 0;
  } else {
    wm = (wid >> 1) * 32; wn = (wid & 1) * 32;
  }
  const int m0 = blockIdx.x * BM, n0 = blockIdx.y * BN;

  floatx4 acc[WR][WC];
#pragma unroll
  for (int i = 0; i < WR; i++)
#pragma unroll
    for (int j = 0; j < WC; j++) acc[i][j] = (floatx4)0.0f;

  for (int kt = 0; kt < K; kt += BK) {
#pragma unroll
    for (int c = 0; c < BM / 64; c++) {
      int seg = c * 64 + wid * 16;
      int row = seg + (lane >> 2);
      int ch = (lane & 3) ^ ((row >> 1) & 3);
      size_t g = (size_t)(m0 + row) * K + kt + ch * 8;
      dma16(&Ah[g], &Ash[seg * BK]);
      dma16(&Al[g], &Asl[seg * BK]);
    }
#pragma unroll
    for (int c = 0; c < BN / 64; c++) {
      int seg = c * 64 + wid * 16;
      int row = seg + (lane >> 2);
      int ch = (lane & 3) ^ ((row >> 1) & 3);
      size_t g = (size_t)(n0 + row) * K + kt + ch * 8;
      dma16(&Wh[g], &Bsh[seg * BK]);
      dma16(&Wl[g], &Bsl[seg * BK]);
    }
    __syncthreads();
    const int kb = lane >> 4;
    short8 ah[WR], al[WR], bh[WC], bl[WC];
#pragma unroll
    for (int i = 0; i < WR; i++) {
      int r = wm + i * 16 + (lane & 15);
      int ro = r * BK + ((kb ^ ((r >> 1) & 3)) << 3);
      ah[i] = *(const short8*)(&Ash[ro]);
      al[i] = *(const short8*)(&Asl[ro]);
    }
#pragma unroll
    for (int j = 0; j < WC; j++) {
      int r = wn + j * 16 + (lane & 15);
      int ro = r * BK + ((kb ^ ((r >> 1) & 3)) << 3);
      bh[j] = *(const short8*)(&Bsh[ro]);
      bl[j] = *(const short8*)(&Bsl[ro]);
    }
#pragma unroll
    for (int i = 0; i < WR; i++)
#pragma unroll
      for (int j = 0; j < WC; j++) {
        acc[i][j] = __builtin_amdgcn_mfma_f32_16x16x32_bf16(bh[j], ah[i],
                                                            acc[i][j], 0, 0, 0);
        acc[i][j] = __builtin_amdgcn_mfma_f32_16x16x32_bf16(bl[j], ah[i],
                                                            acc[i][j], 0, 0, 0);
        acc[i][j] = __builtin_amdgcn_mfma_f32_16x16x32_bf16(bh[j], al[i],
                                                            acc[i][j], 0, 0, 0);
      }
    __syncthreads();
  }

#pragma unroll
  for (int i = 0; i < WR; i++) {
    int row = m0 + wm + i * 16 + (lane & 15);
#pragma unroll
    for (int j = 0; j < WC; j++) {
      int col = n0 + wn + j * 16 + ((lane >> 4) << 2);
      float4 b4 = *(const float4*)&bias[col];
      float bv[4] = {b4.x, b4.y, b4.z, b4.w};
      if constexpr (SPLIT) {
        uint2 uh, ul;
        bf16* hh = (bf16*)&uh;
        bf16* hl = (bf16*)&ul;
#pragma unroll
        for (int r = 0; r < 4; r++) {
          float v = acc[i][j][r] + bv[r];
          float g = 0.5f * v * (1.0f + erff(v * 0.70710678118654752f));
          bf16 hi = __float2bfloat16(g);
          hh[r] = hi;
          hl[r] = __float2bfloat16(g - __bfloat162float(hi));
        }
        *(uint2*)&Chi[(size_t)row * N + col] = uh;
        *(uint2*)&Clo[(size_t)row * N + col] = ul;
      } else {
        *(float4*)&Cf[(size_t)row * N + col] =
            make_float4(acc[i][j][0] + bv[0], acc[i][j][1] + bv[1],
                        acc[i][j][2] + bv[2], acc[i][j][3] + bv[3]);
      }
    }
  }
}

// ------------------------------------------------------- local attention
// qkv_all row stride 3072: [q 0:512 | k 512:1024 | v 1024:1536 | qd|kd|vd]
__global__ __launch_bounds__(256) void local_attn_kernel(
    const bf16* __restrict__ qkv, const void* __restrict__ pm,
    const int* __restrict__ meta, bf16* __restrict__ lo) {
  int lane = threadIdx.x & 63;
  int t = blockIdx.x * 4 + (threadIdx.x >> 6);
  int b = t >> 10, s = t & 1023;
  int h = lane >> 3, sub = lane & 7;
  int flag = meta[0];
  float q[8];
  load8f(qkv + (size_t)t * 3072 + h * 64 + sub * 8, q);
  float sc[4];
  bool val[4];
#pragma unroll
  for (int w = 0; w < 4; w++) {
    int kp = s - 3 + w;
    bool v = (kp >= 0) && !is_pad(pm, flag, b * kS + kp);
    float d = 0.0f;
    if (v) {
      float kk[8];
      load8f(qkv + (size_t)(b * kS + kp) * 3072 + 512 + h * 64 + sub * 8, kk);
#pragma unroll
      for (int e = 0; e < 8; e++) d += q[e] * kk[e];
    }
    d += __shfl_xor(d, 1);
    d += __shfl_xor(d, 2);
    d += __shfl_xor(d, 4);
    sc[w] = v ? d / 8.0f : -INFINITY;
    val[w] = v;
  }
  float mx = fmaxf(fmaxf(sc[0], sc[1]), fmaxf(sc[2], sc[3]));
  float a[4] = {0.f, 0.f, 0.f, 0.f};
  if (mx != -INFINITY) {
    float ssum = 0.f;
#pragma unroll
    for (int w = 0; w < 4; w++) {
      float e = val[w] ? expf(sc[w] - mx) : 0.0f;
      a[w] = e;
      ssum += e;
    }
#pragma unroll
    for (int w = 0; w < 4; w++) a[w] /= ssum;
  }
  float o[8] = {0.f, 0.f, 0.f, 0.f, 0.f, 0.f, 0.f, 0.f};
#pragma unroll
  for (int w = 0; w < 4; w++) {
    if (val[w] && a[w] > 0.0f) {
      int kp = s - 3 + w;
      float vv[8];
      load8f(qkv + (size_t)(b * kS + kp) * 3072 + 1024 + h * 64 + sub * 8, vv);
#pragma unroll
      for (int e = 0; e < 8; e++) o[e] += a[w] * vv[e];
    }
  }
  store8b(lo + (size_t)t * kE + lane * 8, o);
}

// ----------------------------------------------------------- sampler
__global__ __launch_bounds__(256) void sampler_kernel(
    const float* __restrict__ rawf, const void* __restrict__ pm,
    const int* __restrict__ meta, int* __restrict__ sp,
    unsigned int* __restrict__ invm) {
  int t = blockIdx.x * 8 + (threadIdx.x >> 5);
  int p = threadIdx.x & 31;
  int b = t >> 10, s = t & 1023;
  int flag = meta[0];
  float off = 0.0f;
#pragma unroll
  for (int h = 0; h < kH; h++) off += tanhf(rawf[(size_t)t * 256 + h * kP + p]);
  double anchor = 0.1 + 0.8 * (double)p / 31.0;
  double sampled = anchor * (double)s + (double)off;
  double lov = fmax(0.0, (double)s - 256.0);
  sampled = fmin(fmax(sampled, lov), (double)s);
  int vlen = meta[1 + b];
  sampled = fmin(sampled, (double)(vlen - 1));
  int spv = (int)rint(sampled);
  bool inv = is_pad(pm, flag, b * kS + spv) || (spv > s) ||
             (spv >= max(0, s - 3));
  sp[(size_t)t * kP + p] = spv;
  unsigned long long m = __ballot(inv);
  int lane = threadIdx.x & 63;
  if (lane == 0) invm[t] = (unsigned int)m;
  if (lane == 32) invm[t] = (unsigned int)(m >> 32);
}

// ------------------------------------------------------ long attention
// qkv_all: qd at +1536, kd at +2048, vd at +2560 (stride 3072).
__global__ __launch_bounds__(256) void long_attn_kernel(
    const bf16* __restrict__ qkv, const int* __restrict__ sp,
    const unsigned int* __restrict__ invm, bf16* __restrict__ ctx) {
  int lane = threadIdx.x & 63;
  int bid = blockIdx.x;
  int sbid = (bid & 7) * 256 + (bid >> 3);  // XCD-contiguous token ranges
  int t = sbid * 4 + (threadIdx.x >> 6);
  int b = t >> 10;
  int p = lane & 31;
  int row_abs = b * kS + sp[(size_t)t * kP + p];
  float q[8];
  load8f(qkv + (size_t)t * 3072 + 1536 + lane * 8, q);
  float sc_mine = 0.0f;
#pragma unroll 4
  for (int pp = 0; pp < 32; pp++) {
    int row = __shfl(row_abs, pp);
    float kk[8];
    load8f(qkv + (size_t)row * 3072 + 2048 + lane * 8, kk);
    float d = 0.0f;
#pragma unroll
    for (int e = 0; e < 8; e++) d += q[e] * kk[e];
#pragma unroll
    for (int m = 1; m < 64; m <<= 1) d += __shfl_xor(d, m);
    if (p == pp) sc_mine = d;
  }
  bool inv = (invm[t] >> p) & 1u;
  float sc = inv ? -INFINITY : sc_mine / 22.627416997969522f;  // sqrt(512)
  float mx = sc;
#pragma unroll
  for (int m = 1; m < 32; m <<= 1) mx = fmaxf(mx, __shfl_xor(mx, m));
  float e = (inv || mx == -INFINITY) ? 0.0f : expf(sc - mx);
  float ssum = e;
#pragma unroll
  for (int m = 1; m < 32; m <<= 1) ssum += __shfl_xor(ssum, m);
  float a = (ssum > 0.0f) ? e / ssum : 0.0f;
  float o[8] = {0.f, 0.f, 0.f, 0.f, 0.f, 0.f, 0.f, 0.f};
#pragma unroll 4
  for (int pp = 0; pp < 32; pp++) {
    float ap = __shfl(a, pp);
    int row = __shfl(row_abs, pp);
    if (ap != 0.0f) {
      float vv[8];
      load8f(qkv + (size_t)row * 3072 + 2560 + lane * 8, vv);
#pragma unroll
      for (int e2 = 0; e2 < 8; e2++) o[e2] += ap * vv[e2];
    }
  }
  store8b(ctx + (size_t)t * kE + lane * 8, o);
}

// ------------------------------------------------------------------- LN1
__global__ __launch_bounds__(256) void ln1_kernel(
    const void* __restrict__ xin, const int* __restrict__ meta,
    const bf16* __restrict__ lo, const bf16* __restrict__ lg,
    const bf16* __restrict__ g, const float* __restrict__ gamma,
    const float* __restrict__ beta, bf16* __restrict__ x1b,
    float* __restrict__ x1f) {
  int lane = threadIdx.x & 63;
  int t = blockIdx.x * 4 + (threadIdx.x >> 6);
  size_t base = (size_t)t * kE + lane * 8;
  float xv[8], lov[8], lgv[8], gv[8], h[8];
  if (meta[9]) {
    const float4* xf = (const float4*)((const float*)xin + base);
    float4 a = xf[0], b2 = xf[1];
    xv[0] = a.x; xv[1] = a.y; xv[2] = a.z; xv[3] = a.w;
    xv[4] = b2.x; xv[5] = b2.y; xv[6] = b2.z; xv[7] = b2.w;
  } else {
    load8f((const bf16*)xin + base, xv);
  }
  load8f(lo + base, lov);
  load8f(lg + base, lgv);
  load8f(g + base, gv);
  float s1 = 0.f, s2 = 0.f;
#pragma unroll
  for (int e = 0; e < 8; e++) {
    h[e] = xv[e] + gv[e] * lov[e] + (1.0f - gv[e]) * lgv[e];
    s1 += h[e];
    s2 += h[e] * h[e];
  }
#pragma unroll
  for (int m = 1; m < 64; m <<= 1) {
    s1 += __shfl_xor(s1, m);
    s2 += __shfl_xor(s2, m);
  }
  float mean = s1 * (1.0f / kE);
  float var = s2 * (1.0f / kE) - mean * mean;
  float rstd = 1.0f / sqrtf(var + 1e-5f);
  float y[8];
#pragma unroll
  for (int e = 0; e < 8; e++)
    y[e] = (h[e] - mean) * rstd * gamma[lane * 8 + e] + beta[lane * 8 + e];
  store8b(x1b + base, y);
#pragma unroll
  for (int e = 0; e < 8; e++) x1f[base + e] = y[e];
}

// ------------------------------------------------------------------- LN2
__global__ __launch_bounds__(256) void ln2_kernel(
    const float* __restrict__ x1f, const float* __restrict__ ff,
    const float* __restrict__ gamma, const float* __restrict__ beta,
    const int* __restrict__ meta, void* __restrict__ out) {
  int lane = threadIdx.x & 63;
  int t = blockIdx.x * 4 + (threadIdx.x >> 6);
  size_t base = (size_t)t * kE + lane * 8;
  float h[8];
  float s1 = 0.f, s2 = 0.f;
#pragma unroll
  for (int e = 0; e < 8; e++) {
    h[e] = x1f[base + e] + ff[base + e];
    s1 += h[e];
    s2 += h[e] * h[e];
  }
#pragma unroll
  for (int m = 1; m < 64; m <<= 1) {
    s1 += __shfl_xor(s1, m);
    s2 += __shfl_xor(s2, m);
  }
  float mean = s1 * (1.0f / kE);
  float var = s2 * (1.0f / kE) - mean * mean;
  float rstd = 1.0f / sqrtf(var + 1e-5f);
  float y[8];
#pragma unroll
  for (int e = 0; e < 8; e++)
    y[e] = (h[e] - mean) * rstd * gamma[lane * 8 + e] + beta[lane * 8 + e];
  if (meta[9]) {
    float* of = (float*)out + base;
    ((float4*)of)[0] = make_float4(y[0], y[1], y[2], y[3]);
    ((float4*)of)[1] = make_float4(y[4], y[5], y[6], y[7]);
  } else {
    store8b((bf16*)out + base, y);
  }
}

// ------------------------------------------------------------------ launch
extern "C" void kernel_launch(void* const* d_in, const int* in_sizes, int n_in,
                              void* d_out, int out_size, void* d_ws,
                              size_t ws_size, hipStream_t stream) {
  const void* x = d_in[0];
  const void* pm = d_in[1];

  char* w = (char*)d_ws;
  auto alloc = [&](size_t bytes) {
    char* p = w;
    w += (bytes + 255) & ~(size_t)255;
    return p;
  };
  bf16* qkv_all = (bf16*)alloc((size_t)kTok * 3072 * 2);  // recycled later
  bf16* lo_ctx = (bf16*)alloc((size_t)kTok * kE * 2);
  bf16* ctx2 = (bf16*)alloc((size_t)kTok * kE * 2);
  bf16* local_out = (bf16*)alloc((size_t)kTok * kE * 2);
  bf16* long_out = (bf16*)alloc((size_t)kTok * kE * 2);
  bf16* hbuf = (bf16*)alloc((size_t)kTok * kE * 2);    // h_hi / gate hidden
  bf16* gbuf = (bf16*)alloc((size_t)kTok * kE * 2);    // gate out
  bf16* x1b = (bf16*)alloc((size_t)kTok * kE * 2);     // h_lo / x1 bf16
  float* x1f = (float*)alloc((size_t)kTok * kE * 4);   // x1 fp32
  float* rawf = (float*)alloc((size_t)kTok * 256 * 4);
  int* sp = (int*)alloc((size_t)kTok * kP * 4);
  unsigned int* invm = (unsigned int*)alloc((size_t)kTok * 4);
  int* meta = (int*)alloc(256);
  bf16* x_hi = (bf16*)alloc((size_t)kTok * kE * 2);
  bf16* x_lo = (bf16*)alloc((size_t)kTok * kE * 2);
  bf16* wall = (bf16*)alloc((size_t)3072 * 512 * 2);  // ip|dq|dk|dv weights
  bf16* mow = (bf16*)alloc(512 * 512 * 2);
  bf16* dow = (bf16*)alloc(512 * 512 * 2);
  bf16* o1h = (bf16*)alloc(512 * 512 * 2);
  bf16* o1l = (bf16*)alloc(512 * 512 * 2);
  bf16* o2h = (bf16*)alloc(256 * 512 * 2);
  bf16* o2l = (bf16*)alloc(256 * 512 * 2);
  bf16* g1w = (bf16*)alloc(512 * 1536 * 2);
  bf16* g2w = (bf16*)alloc(512 * 512 * 2);
  bf16* f1w = (bf16*)alloc((size_t)2048 * 512 * 2);
  bf16* f2w = (bf16*)alloc((size_t)512 * 2048 * 2);
  float* ball = (float*)alloc(3072 * 4);
  float* mob = (float*)alloc(512 * 4);
  float* dob = (float*)alloc(512 * 4);
  float* o1b = (float*)alloc(512 * 4);
  float* o2b = (float*)alloc(256 * 4);
  float* g1b = (float*)alloc(512 * 4);
  float* g2b = (float*)alloc(512 * 4);
  float* n1g = (float*)alloc(512 * 4);
  float* n1bt = (float*)alloc(512 * 4);
  float* n2g = (float*)alloc(512 * 4);
  float* n2bt = (float*)alloc(512 * 4);
  float* f1b = (float*)alloc(2048 * 4);
  float* f2b = (float*)alloc(512 * 4);

  bf16* h_hi = hbuf;
  bf16* h_lo = x1b;
  float* f_f32 = (float*)qkv_all;                                 // 16.8MB
  bf16* ffn_h = (bf16*)((char*)qkv_all + (size_t)kTok * kE * 4);  // 33.5MB

  dim3 blk(256);
  detect_kernel<<<1, blk, 0, stream>>>(x, meta);
  meta_kernel<<<1, blk, 0, stream>>>(pm, meta);

  // ---- batched ingest (2 launches)
  CvtJobs J;
  auto job = [](const void* s, bf16* hi, bf16* lo, int n) {
    CvtJob j; j.src = s; j.hi = hi; j.lo = lo; j.nblk = n >> 10; return j;
  };
  J.j[0] = job(d_in[0], x_hi, x_lo, kTok * kE);
  J.j[1] = job(d_in[2], wall, nullptr, 1536 * 512);
  J.j[2] = job(d_in[6], wall + (size_t)1536 * 512, nullptr, 512 * 512);
  J.j[3] = job(d_in[8], wall + (size_t)2048 * 512, nullptr, 512 * 512);
  J.j[4] = job(d_in[10], wall + (size_t)2560 * 512, nullptr, 512 * 512);
  J.j[5] = job(d_in[4], mow, nullptr, 512 * 512);
  J.j[6] = job(d_in[12], dow, nullptr, 512 * 512);
  J.j[7] = job(d_in[14], o1h, o1l, 512 * 512);
  J.j[8] = job(d_in[16], o2h, o2l, 256 * 512);
  J.j[9] = job(d_in[18], g1w, nullptr, 512 * 1536);
  J.j[10] = job(d_in[20], g2w, nullptr, 512 * 512);
  J.j[11] = job(d_in[26], f1w, nullptr, 2048 * 512);
  J.j[12] = job(d_in[28], f2w, nullptr, 512 * 2048);
  int totblk = 0;
  for (int i = 0; i < 13; i++) totblk += J.j[i].nblk;
  cvt_all_kernel<<<totblk, blk, 0, stream>>>(J, meta);

  CvtFJobs JF;
  auto fjob = [](const void* s, float* d, int n) {
    CvtFJob j; j.src = s; j.dst = d; j.n = n; return j;
  };
  JF.j[0] = fjob(d_in[3], ball, 1536);
  JF.j[1] = fjob(d_in[7], ball + 1536, 512);
  JF.j[2] = fjob(d_in[9], ball + 2048, 512);
  JF.j[3] = fjob(d_in[11], ball + 2560, 512);
  JF.j[4] = fjob(d_in[5], mob, 512);
  JF.j[5] = fjob(d_in[13], dob, 512);
  JF.j[6] = fjob(d_in[15], o1b, 512);
  JF.j[7] = fjob(d_in[17], o2b, 256);
  JF.j[8] = fjob(d_in[19], g1b, 512);
  JF.j[9] = fjob(d_in[21], g2b, 512);
  JF.j[10] = fjob(d_in[22], n1g, 512);
  JF.j[11] = fjob(d_in[23], n1bt, 512);
  JF.j[12] = fjob(d_in[24], n2g, 512);
  JF.j[13] = fjob(d_in[25], n2bt, 512);
  JF.j[14] = fjob(d_in[27], f1b, 2048);
  JF.j[15] = fjob(d_in[29], f2b, 512);
  cvt_small_kernel<<<1, blk, 0, stream>>>(JF, meta);

  // ---- merged qkv + deformable-qkv projection (N=3072)
  gemm_bt<128, 128, 0, bf16><<<dim3(64, 24), blk, 0, stream>>>(
      x_hi, wall, ball, qkv_all, 3072, kE);
  // ---- offset branch (fused hi/lo triples + fused exact-gelu split)
  gemm3_bt<128, 64, true><<<dim3(64, 8), blk, 0, stream>>>(
      x_hi, x_lo, o1h, o1l, o1b, nullptr, h_hi, h_lo, kE, kE);
  local_attn_kernel<<<2048, blk, 0, stream>>>(qkv_all, pm, meta, lo_ctx);
  gemm3_bt<64, 64, false><<<dim3(128, 4), blk, 0, stream>>>(
      h_hi, h_lo, o2h, o2l, o2b, rawf, nullptr, nullptr, 256, kE);
  sampler_kernel<<<1024, blk, 0, stream>>>(rawf, pm, meta, sp, invm);
  long_attn_kernel<<<2048, blk, 0, stream>>>(qkv_all, sp, invm, ctx2);

  // ---- both attention output projections in one launch
  gemm_pair<<<dim3(64, 16), blk, 0, stream>>>(lo_ctx, mow, mob, local_out,
                                              ctx2, dow, dob, long_out, kE, kE);

  // ---- gate (virtual concat in gate1 staging)
  gemm_gate1<<<dim3(64, 8), blk, 0, stream>>>(x_hi, local_out, long_out, g1w,
                                              g1b, hbuf);
  gemm_bt<128, 64, 2, bf16><<<dim3(64, 8), blk, 0, stream>>>(
      hbuf, g2w, g2b, gbuf, kE, kE);

  // ---- fuse + LN1 + FFN + LN2
  ln1_kernel<<<2048, blk, 0, stream>>>(x, meta, local_out, long_out, gbuf, n1g,
                                       n1bt, x1b, x1f);
  gemm_bt<128, 128, 1, bf16><<<dim3(64, 16), blk, 0, stream>>>(
      x1b, f1w, f1b, ffn_h, kHid, kE);
  gemm_bt<128, 64, 0, float><<<dim3(64, 8), blk, 0, stream>>>(
      ffn_h, f2w, f2b, f_f32, kE, kHid);
  ln2_kernel<<<2048, blk, 0, stream>>>(x1f, f_f32, n2g, n2bt, meta, d_out);
}

// Round 7
// 457.152 us; speedup vs baseline: 1.6377x; 1.0436x over previous
//
#include <hip/hip_runtime.h>
#include <hip/hip_bf16.h>
#include <type_traits>

typedef __hip_bfloat16 bf16;
typedef __attribute__((ext_vector_type(8))) short short8;
typedef __attribute__((ext_vector_type(4))) float floatx4;

static constexpr int kB = 8;
static constexpr int kS = 1024;
static constexpr int kE = 512;
static constexpr int kH = 8;
static constexpr int kP = 32;
static constexpr int kTok = kB * kS;   // 8192
static constexpr int kHid = 2048;

// meta layout: [0]=pm int32 flag, [1..8]=valid_len, [9]=inputs-are-fp32 flag
// ---------------------------------------------------------------- helpers
__device__ __forceinline__ void load8f(const bf16* p, float* f) {
  uint4 u = *(const uint4*)p;
  const bf16* h = (const bf16*)&u;
#pragma unroll
  for (int e = 0; e < 8; e++) f[e] = __bfloat162float(h[e]);
}
__device__ __forceinline__ void store8b(bf16* p, const float* f) {
  uint4 u;
  bf16* h = (bf16*)&u;
#pragma unroll
  for (int e = 0; e < 8; e++) h[e] = __float2bfloat16(f[e]);
  *(uint4*)p = u;
}
__device__ __forceinline__ bool is_pad(const void* pm, int flag, int idx) {
  return flag ? (((const int*)pm)[idx] != 0)
              : (((const unsigned char*)pm)[idx] != 0);
}
__device__ __forceinline__ float fast_gelu(float x) {
  float u = x * (0.7978845608f + 0.044714998f * x * x);
  float e = __expf(2.0f * u);
  float t = 1.0f - 2.0f / (e + 1.0f);
  return 0.5f * x * (1.0f + t);
}
// async global->LDS 16B DMA. dest = wave-uniform lds base + lane*16.
__device__ __forceinline__ void dma16(const bf16* g, bf16* l) {
  __builtin_amdgcn_global_load_lds(
      (const __attribute__((address_space(1))) unsigned int*)g,
      (__attribute__((address_space(3))) unsigned int*)l, 16, 0, 0);
}
// Explicit full drain (vmcnt/lgkmcnt/expcnt = 0). REQUIRED before barriers
// that hand a DMA-written LDS buffer to other waves: global_load_lds has no
// dest VGPR, so the compiler's waitcnt pass can miss the dependence (R6 race).
__device__ __forceinline__ void drain_all() { __builtin_amdgcn_s_waitcnt(0); }

// -------------------------------------------------------- dtype detection
__global__ __launch_bounds__(256) void detect_kernel(const void* __restrict__ x,
                                                     int* __restrict__ meta) {
  __shared__ int cnt;
  if (threadIdx.x == 0) cnt = 0;
  __syncthreads();
  const unsigned short* u = (const unsigned short*)x;
  int c = 0;
  for (int i = threadIdx.x; i < 1024; i += 256) {
    int e = (u[i] >> 7) & 0xFF;
    if (e >= 0x90) c++;
  }
  if (c) atomicAdd(&cnt, c);
  __syncthreads();
  if (threadIdx.x == 0) meta[9] = (cnt > 64) ? 1 : 0;
}

// ------------------------------------------------------------- meta kernel
__global__ __launch_bounds__(256) void meta_kernel(const void* __restrict__ pm,
                                                   int* __restrict__ meta) {
  __shared__ int bigfound;
  __shared__ int cnt[kB];
  int tid = threadIdx.x;
  if (tid == 0) bigfound = 0;
  if (tid < kB) cnt[tid] = 0;
  __syncthreads();
  const unsigned int* w = (const unsigned int*)pm;
  int f = 0;
  for (int i = tid; i < 2048; i += 256)
    if (w[i] & 0xFFFFFFFEu) f = 1;
  if (f) atomicOr(&bigfound, 1);
  __syncthreads();
  int flag = bigfound ? 0 : 1;
  for (int i = tid; i < kTok; i += 256) {
    if (is_pad(pm, flag, i)) atomicAdd(&cnt[i >> 10], 1);
  }
  __syncthreads();
  if (tid == 0) meta[0] = flag;
  if (tid < kB) {
    int vl = kS - cnt[tid];
    if (vl < 1) vl = 1;
    meta[1 + tid] = vl;
  }
}

// ------------------------------------------- batched ingest (one launch)
struct CvtJob { const void* src; bf16* hi; bf16* lo; int nblk; };
struct CvtJobs { CvtJob j[13]; };
__global__ __launch_bounds__(256) void cvt_all_kernel(CvtJobs jobs,
                                                      const int* __restrict__ meta) {
  int fp = meta[9];
  int b = blockIdx.x, ji = 0;
  while (b >= jobs.j[ji].nblk) { b -= jobs.j[ji].nblk; ji++; }
  CvtJob J = jobs.j[ji];
  int i = b * 1024 + threadIdx.x * 4;
  float v[4];
  if (fp) {
    float4 f = ((const float4*)J.src)[i >> 2];
    v[0] = f.x; v[1] = f.y; v[2] = f.z; v[3] = f.w;
  } else {
    uint2 u = *(const uint2*)((const bf16*)J.src + i);
    const bf16* h = (const bf16*)&u;
#pragma unroll
    for (int e = 0; e < 4; e++) v[e] = __bfloat162float(h[e]);
  }
  uint2 uh;
  bf16* hh = (bf16*)&uh;
#pragma unroll
  for (int e = 0; e < 4; e++) hh[e] = __float2bfloat16(v[e]);
  *(uint2*)(J.hi + i) = uh;
  if (J.lo) {
    uint2 ul;
    bf16* hl = (bf16*)&ul;
#pragma unroll
    for (int e = 0; e < 4; e++)
      hl[e] = __float2bfloat16(v[e] - __bfloat162float(hh[e]));
    *(uint2*)(J.lo + i) = ul;
  }
}

struct CvtFJob { const void* src; float* dst; int n; };
struct CvtFJobs { CvtFJob j[16]; };
__global__ __launch_bounds__(256) void cvt_small_kernel(CvtFJobs jobs,
                                                        const int* __restrict__ meta) {
  int fp = meta[9];
#pragma unroll 1
  for (int ji = 0; ji < 16; ji++) {
    CvtFJob J = jobs.j[ji];
    for (int i = threadIdx.x; i < J.n; i += 256)
      J.dst[i] = fp ? ((const float*)J.src)[i]
                    : __bfloat162float(((const bf16*)J.src)[i]);
  }
}

// ------------------------------------------------------------- GEMM core
// C[M,N] = act(A[M,K] @ W[N,K]^T + bias). Staging = global_load_lds dwordx4
// into DOUBLE-BUFFERED LDS: prefetch tile k+1 flies during compute of tile k.
// Explicit drain_all() before each barrier (compiler misses the LDS-DMA
// dependence -> R6 race). LDS rows UNPADDED 64B; chunk slot sigma of row r
// holds global chunk sigma ^ ((r>>1)&3) -> conflict-free ds_read_b128.
// mfma operands swapped: lane's 4 acc regs = 4 consecutive N-cols.
static constexpr int BK = 32;

template <int BM, int BN, int ACT, typename OUTT>
__device__ __forceinline__ void gemm_core(const bf16* __restrict__ A,
                                          const bf16* __restrict__ W,
                                          const float* __restrict__ bias,
                                          OUTT* __restrict__ C, int N, int K,
                                          int m0, int n0) {
  constexpr int WR = (BM == 128 && BN == 128) ? 4 : 2;
  constexpr int WC = 4;
  __shared__ bf16 As[2][BM * BK];
  __shared__ bf16 Bs[2][BN * BK];
  const int tid = threadIdx.x;
  const int lane = tid & 63;
  const int wid = tid >> 6;
  int wm, wn;
  if constexpr (BM == 128 && BN == 128) {
    wm = (wid >> 1) * 64; wn = (wid & 1) * 64;
  } else {  // 128x64
    wm = wid * 32; wn = 0;
  }

  auto stage = [&](int buf, int kt) {
#pragma unroll
    for (int c = 0; c < BM / 64; c++) {
      int seg = c * 64 + wid * 16;
      int row = seg + (lane >> 2);
      int ch = (lane & 3) ^ ((row >> 1) & 3);
      dma16(&A[(size_t)(m0 + row) * K + kt + ch * 8], &As[buf][seg * BK]);
    }
#pragma unroll
    for (int c = 0; c < BN / 64; c++) {
      int seg = c * 64 + wid * 16;
      int row = seg + (lane >> 2);
      int ch = (lane & 3) ^ ((row >> 1) & 3);
      dma16(&W[(size_t)(n0 + row) * K + kt + ch * 8], &Bs[buf][seg * BK]);
    }
  };

  floatx4 acc[WR][WC];
#pragma unroll
  for (int i = 0; i < WR; i++)
#pragma unroll
    for (int j = 0; j < WC; j++) acc[i][j] = (floatx4)0.0f;

  stage(0, 0);
  drain_all();
  __syncthreads();
  const int niter = K / BK;
  for (int k = 0; k < niter; k++) {
    const int cur = k & 1;
    if (k + 1 < niter) stage(cur ^ 1, (k + 1) * BK);  // async, in flight
    const int kb = lane >> 4;
    short8 af[WR], bfr[WC];
#pragma unroll
    for (int i = 0; i < WR; i++) {
      int r = wm + i * 16 + (lane & 15);
      af[i] = *(const short8*)(&As[cur][r * BK + ((kb ^ ((r >> 1) & 3)) << 3)]);
    }
#pragma unroll
    for (int j = 0; j < WC; j++) {
      int r = wn + j * 16 + (lane & 15);
      bfr[j] = *(const short8*)(&Bs[cur][r * BK + ((kb ^ ((r >> 1) & 3)) << 3)]);
    }
#pragma unroll
    for (int i = 0; i < WR; i++)
#pragma unroll
      for (int j = 0; j < WC; j++)
        acc[i][j] = __builtin_amdgcn_mfma_f32_16x16x32_bf16(bfr[j], af[i],
                                                            acc[i][j], 0, 0, 0);
    drain_all();      // prefetch DMA definitely landed
    __syncthreads();  // all waves see it; buffer reuse safe
  }

#pragma unroll
  for (int i = 0; i < WR; i++) {
    int row = m0 + wm + i * 16 + (lane & 15);
#pragma unroll
    for (int j = 0; j < WC; j++) {
      int col = n0 + wn + j * 16 + ((lane >> 4) << 2);
      float bv[4] = {0.f, 0.f, 0.f, 0.f};
      if (bias) {
        float4 b4 = *(const float4*)&bias[col];
        bv[0] = b4.x; bv[1] = b4.y; bv[2] = b4.z; bv[3] = b4.w;
      }
      float v[4];
#pragma unroll
      for (int r = 0; r < 4; r++) {
        v[r] = acc[i][j][r] + bv[r];
        if (ACT == 1) v[r] = fast_gelu(v[r]);
        else if (ACT == 2) v[r] = 1.0f / (1.0f + __expf(-v[r]));
      }
      size_t idx = (size_t)row * N + col;
      if constexpr (std::is_same<OUTT, float>::value) {
        *(float4*)&C[idx] = make_float4(v[0], v[1], v[2], v[3]);
      } else {
        uint2 u;
        bf16* h = (bf16*)&u;
#pragma unroll
        for (int r = 0; r < 4; r++) h[r] = __float2bfloat16(v[r]);
        *(uint2*)&C[idx] = u;
      }
    }
  }
}

template <int BM, int BN, int ACT, typename OUTT>
__global__ __launch_bounds__(256) void gemm_bt(
    const bf16* __restrict__ A, const bf16* __restrict__ W,
    const float* __restrict__ bias, OUTT* __restrict__ C, int N, int K) {
  gemm_core<BM, BN, ACT, OUTT>(A, W, bias, C, N, K, blockIdx.x * BM,
                               blockIdx.y * BN);
}

// two independent E*E GEMMs in one launch (mha_out + do_out)
__global__ __launch_bounds__(256) void gemm_pair(
    const bf16* __restrict__ A0, const bf16* __restrict__ W0,
    const float* __restrict__ b0, bf16* __restrict__ C0,
    const bf16* __restrict__ A1, const bf16* __restrict__ W1,
    const float* __restrict__ b1, bf16* __restrict__ C1, int N, int K) {
  int nb = N >> 6;
  bool s = (int)blockIdx.y >= nb;
  gemm_core<128, 64, 0, bf16>(s ? A1 : A0, s ? W1 : W0, s ? b1 : b0,
                              s ? C1 : C0, N, K, blockIdx.x * 128,
                              (s ? (int)blockIdx.y - nb : (int)blockIdx.y) * 64);
}

// gate1: A is virtual concat [x | local_out | long_out] (K=1536), gelu act.
__global__ __launch_bounds__(256) void gemm_gate1(
    const bf16* __restrict__ x, const bf16* __restrict__ lo,
    const bf16* __restrict__ lg, const bf16* __restrict__ W,
    const float* __restrict__ bias, bf16* __restrict__ C) {
  constexpr int BM = 128, BN = 64, WR = 2, WC = 4;
  constexpr int N = 512, K = 1536;
  __shared__ bf16 As[2][BM * BK];
  __shared__ bf16 Bs[2][BN * BK];
  const int tid = threadIdx.x;
  const int lane = tid & 63;
  const int wid = tid >> 6;
  const int wm = wid * 32, wn = 0;
  const int m0 = blockIdx.x * BM, n0 = blockIdx.y * BN;

  auto stage = [&](int buf, int kt) {
    const bf16* src = (kt < 512) ? x : (kt < 1024) ? lo : lg;
    int kk = kt & 511;
#pragma unroll
    for (int c = 0; c < 2; c++) {
      int seg = c * 64 + wid * 16;
      int row = seg + (lane >> 2);
      int ch = (lane & 3) ^ ((row >> 1) & 3);
      dma16(&src[(size_t)(m0 + row) * 512 + kk + ch * 8], &As[buf][seg * BK]);
    }
    {
      int seg = wid * 16;
      int row = seg + (lane >> 2);
      int ch = (lane & 3) ^ ((row >> 1) & 3);
      dma16(&W[(size_t)(n0 + row) * K + kt + ch * 8], &Bs[buf][seg * BK]);
    }
  };

  floatx4 acc[WR][WC];
#pragma unroll
  for (int i = 0; i < WR; i++)
#pragma unroll
    for (int j = 0; j < WC; j++) acc[i][j] = (floatx4)0.0f;

  stage(0, 0);
  drain_all();
  __syncthreads();
  const int niter = K / BK;
  for (int k = 0; k < niter; k++) {
    const int cur = k & 1;
    if (k + 1 < niter) stage(cur ^ 1, (k + 1) * BK);
    const int kb = lane >> 4;
    short8 af[WR], bfr[WC];
#pragma unroll
    for (int i = 0; i < WR; i++) {
      int r = wm + i * 16 + (lane & 15);
      af[i] = *(const short8*)(&As[cur][r * BK + ((kb ^ ((r >> 1) & 3)) << 3)]);
    }
#pragma unroll
    for (int j = 0; j < WC; j++) {
      int r = wn + j * 16 + (lane & 15);
      bfr[j] = *(const short8*)(&Bs[cur][r * BK + ((kb ^ ((r >> 1) & 3)) << 3)]);
    }
#pragma unroll
    for (int i = 0; i < WR; i++)
#pragma unroll
      for (int j = 0; j < WC; j++)
        acc[i][j] = __builtin_amdgcn_mfma_f32_16x16x32_bf16(bfr[j], af[i],
                                                            acc[i][j], 0, 0, 0);
    drain_all();
    __syncthreads();
  }

#pragma unroll
  for (int i = 0; i < WR; i++) {
    int row = m0 + wm + i * 16 + (lane & 15);
#pragma unroll
    for (int j = 0; j < WC; j++) {
      int col = n0 + wn + j * 16 + ((lane >> 4) << 2);
      float4 b4 = *(const float4*)&bias[col];
      float bv[4] = {b4.x, b4.y, b4.z, b4.w};
      uint2 u;
      bf16* h = (bf16*)&u;
#pragma unroll
      for (int r = 0; r < 4; r++)
        h[r] = __float2bfloat16(fast_gelu(acc[i][j][r] + bv[r]));
      *(uint2*)&C[(size_t)row * N + col] = u;
    }
  }
}

// ---------------------------------------------- fused hi/lo triple GEMM
// acc = Ah@Wh^T (+ Ah@Wl^T if fp) (+ Al@Wh^T if fp||ALWAYS_AL) + bias.
// Offset branch (index-critical). fp = inputs-are-fp32 flag from meta[9]:
// when inputs are bf16, Wl==0 and (for o1) Al==0 -> skip those passes.
// o1: ALWAYS_AL=false (Al=x_lo, zero for bf16). o2: ALWAYS_AL=true (Al=h_lo,
// the gelu-output low bits, nonzero in both modes).
// SPLIT: epilogue applies exact gelu and writes bf16 hi/lo pair.
// Single-buffered (stage->sync->compute->sync, R4/R5-proven).
template <int BM, int BN, bool SPLIT, bool ALWAYS_AL>
__global__ __launch_bounds__(256) void gemm3_bt(
    const bf16* __restrict__ Ah, const bf16* __restrict__ Al,
    const bf16* __restrict__ Wh, const bf16* __restrict__ Wl,
    const float* __restrict__ bias, const int* __restrict__ meta,
    float* __restrict__ Cf, bf16* __restrict__ Chi, bf16* __restrict__ Clo,
    int N, int K) {
  constexpr int WR = 2;
  constexpr int WC = (BM == 128) ? 4 : 2;
  __shared__ bf16 Ash[BM * BK];
  __shared__ bf16 Asl[BM * BK];
  __shared__ bf16 Bsh[BN * BK];
  __shared__ bf16 Bsl[BN * BK];
  const int fp = meta[9];
  const bool use_al = fp || ALWAYS_AL;
  const int tid = threadIdx.x;
  const int lane = tid & 63;
  const int wid = tid >> 6;
  int wm, wn;
  if constexpr (BM == 128) {
    wm = wid * 32; wn = 0;
  } else {
    wm = (wid >> 1) * 32; wn = (wid & 1) * 32;
  }
  const int m0 = blockIdx.x * BM, n0 = blockIdx.y * BN;

  floatx4 acc[WR][WC];
#pragma unroll
  for (int i = 0; i < WR; i++)
#pragma unroll
    for (int j = 0; j < WC; j++) acc[i][j] = (floatx4)0.0f;

  for (int kt = 0; kt < K; kt += BK) {
#pragma unroll
    for (int c = 0; c < BM / 64; c++) {
      int seg = c * 64 + wid * 16;
      int row = seg + (lane >> 2);
      int ch = (lane & 3) ^ ((row >> 1) & 3);
      size_t g = (size_t)(m0 + row) * K + kt + ch * 8;
      dma16(&Ah[g], &Ash[seg * BK]);
      if (use_al) dma16(&Al[g], &Asl[seg * BK]);
    }
#pragma unroll
    for (int c = 0; c < BN / 64; c++) {
      int seg = c * 64 + wid * 16;
      int row = seg + (lane >> 2);
      int ch = (lane & 3) ^ ((row >> 1) & 3);
      size_t g = (size_t)(n0 + row) * K + kt + ch * 8;
      dma16(&Wh[g], &Bsh[seg * BK]);
      if (fp) dma16(&Wl[g], &Bsl[seg * BK]);
    }
    drain_all();
    __syncthreads();
    const int kb = lane >> 4;
    short8 ah[WR], al[WR], bh[WC], bl[WC];
#pragma unroll
    for (int i = 0; i < WR; i++) {
      int r = wm + i * 16 + (lane & 15);
      int ro = r * BK + ((kb ^ ((r >> 1) & 3)) << 3);
      ah[i] = *(const short8*)(&Ash[ro]);
      if (use_al) al[i] = *(const short8*)(&Asl[ro]);
    }
#pragma unroll
    for (int j = 0; j < WC; j++) {
      int r = wn + j * 16 + (lane & 15);
      int ro = r * BK + ((kb ^ ((r >> 1) & 3)) << 3);
      bh[j] = *(const short8*)(&Bsh[ro]);
      if (fp) bl[j] = *(const short8*)(&Bsl[ro]);
    }
#pragma unroll
    for (int i = 0; i < WR; i++)
#pragma unroll
      for (int j = 0; j < WC; j++) {
        acc[i][j] = __builtin_amdgcn_mfma_f32_16x16x32_bf16(bh[j], ah[i],
                                                            acc[i][j], 0, 0, 0);
        if (fp)
          acc[i][j] = __builtin_amdgcn_mfma_f32_16x16x32_bf16(
              bl[j], ah[i], acc[i][j], 0, 0, 0);
        if (use_al)
          acc[i][j] = __builtin_amdgcn_mfma_f32_16x16x32_bf16(
              bh[j], al[i], acc[i][j], 0, 0, 0);
      }
    __syncthreads();
  }

#pragma unroll
  for (int i = 0; i < WR; i++) {
    int row = m0 + wm + i * 16 + (lane & 15);
#pragma unroll
    for (int j = 0; j < WC; j++) {
      int col = n0 + wn + j * 16 + ((lane >> 4) << 2);
      float4 b4 = *(const float4*)&bias[col];
      float bv[4] = {b4.x, b4.y, b4.z, b4.w};
      if constexpr (SPLIT) {
        uint2 uh, ul;
        bf16* hh = (bf16*)&uh;
        bf16* hl = (bf16*)&ul;
#pragma unroll
        for (int r = 0; r < 4; r++) {
          float v = acc[i][j][r] + bv[r];
          float g = 0.5f * v * (1.0f + erff(v * 0.70710678118654752f));
          bf16 hi = __float2bfloat16(g);
          hh[r] = hi;
          hl[r] = __float2bfloat16(g - __bfloat162float(hi));
        }
        *(uint2*)&Chi[(size_t)row * N + col] = uh;
        *(uint2*)&Clo[(size_t)row * N + col] = ul;
      } else {
        *(float4*)&Cf[(size_t)row * N + col] =
            make_float4(acc[i][j][0] + bv[0], acc[i][j][1] + bv[1],
                        acc[i][j][2] + bv[2], acc[i][j][3] + bv[3]);
      }
    }
  }
}

// ------------------------------------------------------- local attention
// qkv_all row stride 3072: [q 0:512 | k 512:1024 | v 1024:1536 | qd|kd|vd]
__global__ __launch_bounds__(256) void local_attn_kernel(
    const bf16* __restrict__ qkv, const void* __restrict__ pm,
    const int* __restrict__ meta, bf16* __restrict__ lo) {
  int lane = threadIdx.x & 63;
  int t = blockIdx.x * 4 + (threadIdx.x >> 6);
  int b = t >> 10, s = t & 1023;
  int h = lane >> 3, sub = lane & 7;
  int flag = meta[0];
  float q[8];
  load8f(qkv + (size_t)t * 3072 + h * 64 + sub * 8, q);
  float sc[4];
  bool val[4];
#pragma unroll
  for (int w = 0; w < 4; w++) {
    int kp = s - 3 + w;
    bool v = (kp >= 0) && !is_pad(pm, flag, b * kS + kp);
    float d = 0.0f;
    if (v) {
      float kk[8];
      load8f(qkv + (size_t)(b * kS + kp) * 3072 + 512 + h * 64 + sub * 8, kk);
#pragma unroll
      for (int e = 0; e < 8; e++) d += q[e] * kk[e];
    }
    d += __shfl_xor(d, 1);
    d += __shfl_xor(d, 2);
    d += __shfl_xor(d, 4);
    sc[w] = v ? d / 8.0f : -INFINITY;
    val[w] = v;
  }
  float mx = fmaxf(fmaxf(sc[0], sc[1]), fmaxf(sc[2], sc[3]));
  float a[4] = {0.f, 0.f, 0.f, 0.f};
  if (mx != -INFINITY) {
    float ssum = 0.f;
#pragma unroll
    for (int w = 0; w < 4; w++) {
      float e = val[w] ? expf(sc[w] - mx) : 0.0f;
      a[w] = e;
      ssum += e;
    }
#pragma unroll
    for (int w = 0; w < 4; w++) a[w] /= ssum;
  }
  float o[8] = {0.f, 0.f, 0.f, 0.f, 0.f, 0.f, 0.f, 0.f};
#pragma unroll
  for (int w = 0; w < 4; w++) {
    if (val[w] && a[w] > 0.0f) {
      int kp = s - 3 + w;
      float vv[8];
      load8f(qkv + (size_t)(b * kS + kp) * 3072 + 1024 + h * 64 + sub * 8, vv);
#pragma unroll
      for (int e = 0; e < 8; e++) o[e] += a[w] * vv[e];
    }
  }
  store8b(lo + (size_t)t * kE + lane * 8, o);
}

// ----------------------------------------------------------- sampler
__global__ __launch_bounds__(256) void sampler_kernel(
    const float* __restrict__ rawf, const void* __restrict__ pm,
    const int* __restrict__ meta, int* __restrict__ sp,
    unsigned int* __restrict__ invm) {
  int t = blockIdx.x * 8 + (threadIdx.x >> 5);
  int p = threadIdx.x & 31;
  int b = t >> 10, s = t & 1023;
  int flag = meta[0];
  float off = 0.0f;
#pragma unroll
  for (int h = 0; h < kH; h++) off += tanhf(rawf[(size_t)t * 256 + h * kP + p]);
  double anchor = 0.1 + 0.8 * (double)p / 31.0;
  double sampled = anchor * (double)s + (double)off;
  double lov = fmax(0.0, (double)s - 256.0);
  sampled = fmin(fmax(sampled, lov), (double)s);
  int vlen = meta[1 + b];
  sampled = fmin(sampled, (double)(vlen - 1));
  int spv = (int)rint(sampled);
  bool inv = is_pad(pm, flag, b * kS + spv) || (spv > s) ||
             (spv >= max(0, s - 3));
  sp[(size_t)t * kP + p] = spv;
  unsigned long long m = __ballot(inv);
  int lane = threadIdx.x & 63;
  if (lane == 0) invm[t] = (unsigned int)m;
  if (lane == 32) invm[t] = (unsigned int)(m >> 32);
}

// ------------------------------------------------------ long attention
// qkv_all: qd at +1536, kd at +2048, vd at +2560 (stride 3072).
__global__ __launch_bounds__(256) void long_attn_kernel(
    const bf16* __restrict__ qkv, const int* __restrict__ sp,
    const unsigned int* __restrict__ invm, bf16* __restrict__ ctx) {
  int lane = threadIdx.x & 63;
  int bid = blockIdx.x;
  int sbid = (bid & 7) * 256 + (bid >> 3);  // XCD-contiguous token ranges
  int t = sbid * 4 + (threadIdx.x >> 6);
  int b = t >> 10;
  int p = lane & 31;
  int row_abs = b * kS + sp[(size_t)t * kP + p];
  float q[8];
  load8f(qkv + (size_t)t * 3072 + 1536 + lane * 8, q);
  float sc_mine = 0.0f;
#pragma unroll 4
  for (int pp = 0; pp < 32; pp++) {
    int row = __shfl(row_abs, pp);
    float kk[8];
    load8f(qkv + (size_t)row * 3072 + 2048 + lane * 8, kk);
    float d = 0.0f;
#pragma unroll
    for (int e = 0; e < 8; e++) d += q[e] * kk[e];
#pragma unroll
    for (int m = 1; m < 64; m <<= 1) d += __shfl_xor(d, m);
    if (p == pp) sc_mine = d;
  }
  bool inv = (invm[t] >> p) & 1u;
  float sc = inv ? -INFINITY : sc_mine / 22.627416997969522f;  // sqrt(512)
  float mx = sc;
#pragma unroll
  for (int m = 1; m < 32; m <<= 1) mx = fmaxf(mx, __shfl_xor(mx, m));
  float e = (inv || mx == -INFINITY) ? 0.0f : expf(sc - mx);
  float ssum = e;
#pragma unroll
  for (int m = 1; m < 32; m <<= 1) ssum += __shfl_xor(ssum, m);
  float a = (ssum > 0.0f) ? e / ssum : 0.0f;
  float o[8] = {0.f, 0.f, 0.f, 0.f, 0.f, 0.f, 0.f, 0.f};
#pragma unroll 4
  for (int pp = 0; pp < 32; pp++) {
    float ap = __shfl(a, pp);
    int row = __shfl(row_abs, pp);
    if (ap != 0.0f) {
      float vv[8];
      load8f(qkv + (size_t)row * 3072 + 2560 + lane * 8, vv);
#pragma unroll
      for (int e2 = 0; e2 < 8; e2++) o[e2] += ap * vv[e2];
    }
  }
  store8b(ctx + (size_t)t * kE + lane * 8, o);
}

// ------------------------------------------------------------------- LN1
__global__ __launch_bounds__(256) void ln1_kernel(
    const void* __restrict__ xin, const int* __restrict__ meta,
    const bf16* __restrict__ lo, const bf16* __restrict__ lg,
    const bf16* __restrict__ g, const float* __restrict__ gamma,
    const float* __restrict__ beta, bf16* __restrict__ x1b,
    float* __restrict__ x1f) {
  int lane = threadIdx.x & 63;
  int t = blockIdx.x * 4 + (threadIdx.x >> 6);
  size_t base = (size_t)t * kE + lane * 8;
  float xv[8], lov[8], lgv[8], gv[8], h[8];
  if (meta[9]) {
    const float4* xf = (const float4*)((const float*)xin + base);
    float4 a = xf[0], b2 = xf[1];
    xv[0] = a.x; xv[1] = a.y; xv[2] = a.z; xv[3] = a.w;
    xv[4] = b2.x; xv[5] = b2.y; xv[6] = b2.z; xv[7] = b2.w;
  } else {
    load8f((const bf16*)xin + base, xv);
  }
  load8f(lo + base, lov);
  load8f(lg + base, lgv);
  load8f(g + base, gv);
  float s1 = 0.f, s2 = 0.f;
#pragma unroll
  for (int e = 0; e < 8; e++) {
    h[e] = xv[e] + gv[e] * lov[e] + (1.0f - gv[e]) * lgv[e];
    s1 += h[e];
    s2 += h[e] * h[e];
  }
#pragma unroll
  for (int m = 1; m < 64; m <<= 1) {
    s1 += __shfl_xor(s1, m);
    s2 += __shfl_xor(s2, m);
  }
  float mean = s1 * (1.0f / kE);
  float var = s2 * (1.0f / kE) - mean * mean;
  float rstd = 1.0f / sqrtf(var + 1e-5f);
  float y[8];
#pragma unroll
  for (int e = 0; e < 8; e++)
    y[e] = (h[e] - mean) * rstd * gamma[lane * 8 + e] + beta[lane * 8 + e];
  store8b(x1b + base, y);
#pragma unroll
  for (int e = 0; e < 8; e++) x1f[base + e] = y[e];
}

// ------------------------------------------------------------------- LN2
__global__ __launch_bounds__(256) void ln2_kernel(
    const float* __restrict__ x1f, const float* __restrict__ ff,
    const float* __restrict__ gamma, const float* __restrict__ beta,
    const int* __restrict__ meta, void* __restrict__ out) {
  int lane = threadIdx.x & 63;
  int t = blockIdx.x * 4 + (threadIdx.x >> 6);
  size_t base = (size_t)t * kE + lane * 8;
  float h[8];
  float s1 = 0.f, s2 = 0.f;
#pragma unroll
  for (int e = 0; e < 8; e++) {
    h[e] = x1f[base + e] + ff[base + e];
    s1 += h[e];
    s2 += h[e] * h[e];
  }
#pragma unroll
  for (int m = 1; m < 64; m <<= 1) {
    s1 += __shfl_xor(s1, m);
    s2 += __shfl_xor(s2, m);
  }
  float mean = s1 * (1.0f / kE);
  float var = s2 * (1.0f / kE) - mean * mean;
  float rstd = 1.0f / sqrtf(var + 1e-5f);
  float y[8];
#pragma unroll
  for (int e = 0; e < 8; e++)
    y[e] = (h[e] - mean) * rstd * gamma[lane * 8 + e] + beta[lane * 8 + e];
  if (meta[9]) {
    float* of = (float*)out + base;
    ((float4*)of)[0] = make_float4(y[0], y[1], y[2], y[3]);
    ((float4*)of)[1] = make_float4(y[4], y[5], y[6], y[7]);
  } else {
    store8b((bf16*)out + base, y);
  }
}

// ------------------------------------------------------------------ launch
extern "C" void kernel_launch(void* const* d_in, const int* in_sizes, int n_in,
                              void* d_out, int out_size, void* d_ws,
                              size_t ws_size, hipStream_t stream) {
  const void* x = d_in[0];
  const void* pm = d_in[1];

  char* w = (char*)d_ws;
  auto alloc = [&](size_t bytes) {
    char* p = w;
    w += (bytes + 255) & ~(size_t)255;
    return p;
  };
  bf16* qkv_all = (bf16*)alloc((size_t)kTok * 3072 * 2);  // recycled later
  bf16* lo_ctx = (bf16*)alloc((size_t)kTok * kE * 2);
  bf16* ctx2 = (bf16*)alloc((size_t)kTok * kE * 2);
  bf16* local_out = (bf16*)alloc((size_t)kTok * kE * 2);
  bf16* long_out = (bf16*)alloc((size_t)kTok * kE * 2);
  bf16* hbuf = (bf16*)alloc((size_t)kTok * kE * 2);    // h_hi / gate hidden
  bf16* gbuf = (bf16*)alloc((size_t)kTok * kE * 2);    // gate out
  bf16* x1b = (bf16*)alloc((size_t)kTok * kE * 2);     // h_lo / x1 bf16
  float* x1f = (float*)alloc((size_t)kTok * kE * 4);   // x1 fp32
  float* rawf = (float*)alloc((size_t)kTok * 256 * 4);
  int* sp = (int*)alloc((size_t)kTok * kP * 4);
  unsigned int* invm = (unsigned int*)alloc((size_t)kTok * 4);
  int* meta = (int*)alloc(256);
  bf16* x_hi = (bf16*)alloc((size_t)kTok * kE * 2);
  bf16* x_lo = (bf16*)alloc((size_t)kTok * kE * 2);
  bf16* wall = (bf16*)alloc((size_t)3072 * 512 * 2);  // ip|dq|dk|dv weights
  bf16* mow = (bf16*)alloc(512 * 512 * 2);
  bf16* dow = (bf16*)alloc(512 * 512 * 2);
  bf16* o1h = (bf16*)alloc(512 * 512 * 2);
  bf16* o1l = (bf16*)alloc(512 * 512 * 2);
  bf16* o2h = (bf16*)alloc(256 * 512 * 2);
  bf16* o2l = (bf16*)alloc(256 * 512 * 2);
  bf16* g1w = (bf16*)alloc(512 * 1536 * 2);
  bf16* g2w = (bf16*)alloc(512 * 512 * 2);
  bf16* f1w = (bf16*)alloc((size_t)2048 * 512 * 2);
  bf16* f2w = (bf16*)alloc((size_t)512 * 2048 * 2);
  float* ball = (float*)alloc(3072 * 4);
  float* mob = (float*)alloc(512 * 4);
  float* dob = (float*)alloc(512 * 4);
  float* o1b = (float*)alloc(512 * 4);
  float* o2b = (float*)alloc(256 * 4);
  float* g1b = (float*)alloc(512 * 4);
  float* g2b = (float*)alloc(512 * 4);
  float* n1g = (float*)alloc(512 * 4);
  float* n1bt = (float*)alloc(512 * 4);
  float* n2g = (float*)alloc(512 * 4);
  float* n2bt = (float*)alloc(512 * 4);
  float* f1b = (float*)alloc(2048 * 4);
  float* f2b = (float*)alloc(512 * 4);

  bf16* h_hi = hbuf;
  bf16* h_lo = x1b;
  float* f_f32 = (float*)qkv_all;                                 // 16.8MB
  bf16* ffn_h = (bf16*)((char*)qkv_all + (size_t)kTok * kE * 4);  // 33.5MB

  dim3 blk(256);
  detect_kernel<<<1, blk, 0, stream>>>(x, meta);
  meta_kernel<<<1, blk, 0, stream>>>(pm, meta);

  // ---- batched ingest (2 launches)
  CvtJobs J;
  auto job = [](const void* s, bf16* hi, bf16* lo, int n) {
    CvtJob j; j.src = s; j.hi = hi; j.lo = lo; j.nblk = n >> 10; return j;
  };
  J.j[0] = job(d_in[0], x_hi, x_lo, kTok * kE);
  J.j[1] = job(d_in[2], wall, nullptr, 1536 * 512);
  J.j[2] = job(d_in[6], wall + (size_t)1536 * 512, nullptr, 512 * 512);
  J.j[3] = job(d_in[8], wall + (size_t)2048 * 512, nullptr, 512 * 512);
  J.j[4] = job(d_in[10], wall + (size_t)2560 * 512, nullptr, 512 * 512);
  J.j[5] = job(d_in[4], mow, nullptr, 512 * 512);
  J.j[6] = job(d_in[12], dow, nullptr, 512 * 512);
  J.j[7] = job(d_in[14], o1h, o1l, 512 * 512);
  J.j[8] = job(d_in[16], o2h, o2l, 256 * 512);
  J.j[9] = job(d_in[18], g1w, nullptr, 512 * 1536);
  J.j[10] = job(d_in[20], g2w, nullptr, 512 * 512);
  J.j[11] = job(d_in[26], f1w, nullptr, 2048 * 512);
  J.j[12] = job(d_in[28], f2w, nullptr, 512 * 2048);
  int totblk = 0;
  for (int i = 0; i < 13; i++) totblk += J.j[i].nblk;
  cvt_all_kernel<<<totblk, blk, 0, stream>>>(J, meta);

  CvtFJobs JF;
  auto fjob = [](const void* s, float* d, int n) {
    CvtFJob j; j.src = s; j.dst = d; j.n = n; return j;
  };
  JF.j[0] = fjob(d_in[3], ball, 1536);
  JF.j[1] = fjob(d_in[7], ball + 1536, 512);
  JF.j[2] = fjob(d_in[9], ball + 2048, 512);
  JF.j[3] = fjob(d_in[11], ball + 2560, 512);
  JF.j[4] = fjob(d_in[5], mob, 512);
  JF.j[5] = fjob(d_in[13], dob, 512);
  JF.j[6] = fjob(d_in[15], o1b, 512);
  JF.j[7] = fjob(d_in[17], o2b, 256);
  JF.j[8] = fjob(d_in[19], g1b, 512);
  JF.j[9] = fjob(d_in[21], g2b, 512);
  JF.j[10] = fjob(d_in[22], n1g, 512);
  JF.j[11] = fjob(d_in[23], n1bt, 512);
  JF.j[12] = fjob(d_in[24], n2g, 512);
  JF.j[13] = fjob(d_in[25], n2bt, 512);
  JF.j[14] = fjob(d_in[27], f1b, 2048);
  JF.j[15] = fjob(d_in[29], f2b, 512);
  cvt_small_kernel<<<1, blk, 0, stream>>>(JF, meta);

  // ---- merged qkv + deformable-qkv projection (N=3072)
  gemm_bt<128, 128, 0, bf16><<<dim3(64, 24), blk, 0, stream>>>(
      x_hi, wall, ball, qkv_all, 3072, kE);
  // ---- offset branch (hi/lo triples w/ bf16 fast path + fused gelu split)
  gemm3_bt<128, 64, true, false><<<dim3(64, 8), blk, 0, stream>>>(
      x_hi, x_lo, o1h, o1l, o1b, meta, nullptr, h_hi, h_lo, kE, kE);
  local_attn_kernel<<<2048, blk, 0, stream>>>(qkv_all, pm, meta, lo_ctx);
  gemm3_bt<64, 64, false, true><<<dim3(128, 4), blk, 0, stream>>>(
      h_hi, h_lo, o2h, o2l, o2b, meta, rawf, nullptr, nullptr, 256, kE);
  sampler_kernel<<<1024, blk, 0, stream>>>(rawf, pm, meta, sp, invm);
  long_attn_kernel<<<2048, blk, 0, stream>>>(qkv_all, sp, invm, ctx2);

  // ---- both attention output projections in one launch
  gemm_pair<<<dim3(64, 16), blk, 0, stream>>>(lo_ctx, mow, mob, local_out,
                                              ctx2, dow, dob, long_out, kE, kE);

  // ---- gate (virtual concat in gate1 staging)
  gemm_gate1<<<dim3(64, 8), blk, 0, stream>>>(x_hi, local_out, long_out, g1w,
                                              g1b, hbuf);
  gemm_bt<128, 64, 2, bf16><<<dim3(64, 8), blk, 0, stream>>>(
      hbuf, g2w, g2b, gbuf, kE, kE);

  // ---- fuse + LN1 + FFN + LN2
  ln1_kernel<<<2048, blk, 0, stream>>>(x, meta, local_out, long_out, gbuf, n1g,
                                       n1bt, x1b, x1f);
  gemm_bt<128, 128, 1, bf16><<<dim3(64, 16), blk, 0, stream>>>(
      x1b, f1w, f1b, ffn_h, kHid, kE);
  gemm_bt<128, 64, 0, float><<<dim3(64, 8), blk, 0, stream>>>(
      ffn_h, f2w, f2b, f_f32, kE, kHid);
  ln2_kernel<<<2048, blk, 0, stream>>>(x1f, f_f32, n2g, n2bt, meta, d_out);
}